// Round 1
// baseline (419.880 us; speedup 1.0000x reference)
//
#include <hip/hip_runtime.h>

// Problem constants: B=8, T=1024, DIM=512, H=8, DK=64, L=32, DH=512, DOUT=512
// qkv buffer layout: [1536][8192] where row o = {q:0..511, k:512..1023, v:1024..1535},
// col = b*1024 + t.  n = b*8 + h; row for (q,h,d) = h*64+d.

// ---------------- GEMM NT: C[M][N] = A[M][K] * B[N][K]^T ----------------
__global__ __launch_bounds__(256) void gemm_nt(const float* __restrict__ A,
                                               const float* __restrict__ B,
                                               float* __restrict__ C,
                                               int M, int N, int K) {
  __shared__ float As[16][132];
  __shared__ float Bs[16][132];
  const int tid = threadIdx.x;
  const int bm = blockIdx.y * 128;
  const int bn = blockIdx.x * 128;
  const int lrow = tid >> 1;        // 0..127
  const int lk = (tid & 1) * 8;     // 0 or 8
  const float* Ap = A + (size_t)(bm + lrow) * K + lk;
  const float* Bp = B + (size_t)(bn + lrow) * K + lk;
  const int tx = tid & 15, ty = tid >> 4;
  float acc[8][8] = {{0.f}};
  for (int k0 = 0; k0 < K; k0 += 16) {
    float4 a0 = *(const float4*)(Ap + k0);
    float4 a1 = *(const float4*)(Ap + k0 + 4);
    float4 b0 = *(const float4*)(Bp + k0);
    float4 b1 = *(const float4*)(Bp + k0 + 4);
    As[lk+0][lrow] = a0.x; As[lk+1][lrow] = a0.y; As[lk+2][lrow] = a0.z; As[lk+3][lrow] = a0.w;
    As[lk+4][lrow] = a1.x; As[lk+5][lrow] = a1.y; As[lk+6][lrow] = a1.z; As[lk+7][lrow] = a1.w;
    Bs[lk+0][lrow] = b0.x; Bs[lk+1][lrow] = b0.y; Bs[lk+2][lrow] = b0.z; Bs[lk+3][lrow] = b0.w;
    Bs[lk+4][lrow] = b1.x; Bs[lk+5][lrow] = b1.y; Bs[lk+6][lrow] = b1.z; Bs[lk+7][lrow] = b1.w;
    __syncthreads();
#pragma unroll
    for (int k = 0; k < 16; ++k) {
      float4 av0 = *(const float4*)&As[k][ty * 8];
      float4 av1 = *(const float4*)&As[k][ty * 8 + 4];
      float4 bv0 = *(const float4*)&Bs[k][tx * 8];
      float4 bv1 = *(const float4*)&Bs[k][tx * 8 + 4];
      float a_[8] = {av0.x, av0.y, av0.z, av0.w, av1.x, av1.y, av1.z, av1.w};
      float b_[8] = {bv0.x, bv0.y, bv0.z, bv0.w, bv1.x, bv1.y, bv1.z, bv1.w};
#pragma unroll
      for (int i = 0; i < 8; ++i)
#pragma unroll
        for (int j = 0; j < 8; ++j)
          acc[i][j] = fmaf(a_[i], b_[j], acc[i][j]);
    }
    __syncthreads();
  }
#pragma unroll
  for (int i = 0; i < 8; ++i) {
    float* Cp = C + (size_t)(bm + ty * 8 + i) * N + bn + tx * 8;
    float4 r0 = {acc[i][0], acc[i][1], acc[i][2], acc[i][3]};
    float4 r1 = {acc[i][4], acc[i][5], acc[i][6], acc[i][7]};
    *(float4*)Cp = r0;
    *(float4*)(Cp + 4) = r1;
  }
}

// ------------- GEMM NN + bias: y[b,o,t] = sum_d Wout[o,d]*out[b,d,t] + bias[o] -------------
__global__ __launch_bounds__(256) void gemm_nn_bias(const float* __restrict__ A,
                                                    const float* __restrict__ Bfull,
                                                    const float* __restrict__ bias,
                                                    float* __restrict__ C) {
  __shared__ float As[16][132];
  __shared__ float Bs[16][132];
  const int tid = threadIdx.x;
  const int bm = blockIdx.y * 128;
  const int colg = blockIdx.x * 128;
  const int b = colg >> 10;
  const int t0 = colg & 1023;
  const int K = 512;
  const float* Bb = Bfull + (size_t)b * 512 * 1024 + t0;
  const int lrow = tid >> 1, lk = (tid & 1) * 8;
  const float* Ap = A + (size_t)(bm + lrow) * K + lk;
  const int bk = tid >> 4;          // 0..15
  const int bq = (tid & 15) * 8;    // 0..120
  const int tx = tid & 15, ty = tid >> 4;
  float acc[8][8] = {{0.f}};
  for (int k0 = 0; k0 < K; k0 += 16) {
    float4 a0 = *(const float4*)(Ap + k0);
    float4 a1 = *(const float4*)(Ap + k0 + 4);
    const float* bp = Bb + (size_t)(k0 + bk) * 1024 + bq;
    float4 b0 = *(const float4*)(bp);
    float4 b1 = *(const float4*)(bp + 4);
    As[lk+0][lrow] = a0.x; As[lk+1][lrow] = a0.y; As[lk+2][lrow] = a0.z; As[lk+3][lrow] = a0.w;
    As[lk+4][lrow] = a1.x; As[lk+5][lrow] = a1.y; As[lk+6][lrow] = a1.z; As[lk+7][lrow] = a1.w;
    *(float4*)&Bs[bk][bq] = b0;
    *(float4*)&Bs[bk][bq + 4] = b1;
    __syncthreads();
#pragma unroll
    for (int k = 0; k < 16; ++k) {
      float4 av0 = *(const float4*)&As[k][ty * 8];
      float4 av1 = *(const float4*)&As[k][ty * 8 + 4];
      float4 bv0 = *(const float4*)&Bs[k][tx * 8];
      float4 bv1 = *(const float4*)&Bs[k][tx * 8 + 4];
      float a_[8] = {av0.x, av0.y, av0.z, av0.w, av1.x, av1.y, av1.z, av1.w};
      float b_[8] = {bv0.x, bv0.y, bv0.z, bv0.w, bv1.x, bv1.y, bv1.z, bv1.w};
#pragma unroll
      for (int i = 0; i < 8; ++i)
#pragma unroll
        for (int j = 0; j < 8; ++j)
          acc[i][j] = fmaf(a_[i], b_[j], acc[i][j]);
    }
    __syncthreads();
  }
#pragma unroll
  for (int i = 0; i < 8; ++i) {
    int m = bm + ty * 8 + i;
    float bb = bias[m];
    float* Cp = C + (size_t)b * 524288 + (size_t)m * 1024 + t0 + tx * 8;
    float4 r0 = {acc[i][0] + bb, acc[i][1] + bb, acc[i][2] + bb, acc[i][3] + bb};
    float4 r1 = {acc[i][4] + bb, acc[i][5] + bb, acc[i][6] + bb, acc[i][7] + bb};
    *(float4*)Cp = r0;
    *(float4*)(Cp + 4) = r1;
  }
}

// ---------------- softmax over t for each k row ----------------
__global__ __launch_bounds__(256) void softmax_k(float* __restrict__ qkv) {
  const int r = blockIdx.x;           // 0..4095
  const int hd = r >> 3, b = r & 7;
  float* row = qkv + (size_t)(512 + hd) * 8192 + b * 1024;
  const int tid = threadIdx.x;
  float4 x = *(const float4*)(row + tid * 4);
  float m = fmaxf(fmaxf(x.x, x.y), fmaxf(x.z, x.w));
#pragma unroll
  for (int off = 32; off; off >>= 1) m = fmaxf(m, __shfl_down(m, off));
  __shared__ float red1[4];
  __shared__ float red2[4];
  const int w = tid >> 6, lane = tid & 63;
  if (lane == 0) red1[w] = m;
  __syncthreads();
  m = fmaxf(fmaxf(red1[0], red1[1]), fmaxf(red1[2], red1[3]));
  float4 e;
  e.x = __expf(x.x - m); e.y = __expf(x.y - m); e.z = __expf(x.z - m); e.w = __expf(x.w - m);
  float s = e.x + e.y + e.z + e.w;
#pragma unroll
  for (int off = 32; off; off >>= 1) s += __shfl_down(s, off);
  if (lane == 0) red2[w] = s;
  __syncthreads();
  float inv = 1.0f / (red2[0] + red2[1] + red2[2] + red2[3]);
  e.x *= inv; e.y *= inv; e.z *= inv; e.w *= inv;
  *(float4*)(row + tid * 4) = e;
}

// ---------------- PsumT[d][t] = sum over valid j of rel_positions[j][d] ----------------
__global__ __launch_bounds__(256) void psum_kernel(const float* __restrict__ relpos,
                                                   float* __restrict__ PsumT) {
  const int d = blockIdx.y;
  const int t = blockIdx.x * 256 + threadIdx.x;
  float acc = 0.f;
  for (int j = 0; j < 63; ++j) {
    int i = t + j - 31;
    float v = relpos[j * 64 + d];
    if (i >= 0 && i < 1024) acc += v;
  }
  PsumT[d * 1024 + t] = acc;
}

// ---------------- context partials: ctx_part[chunk][n][d][e] = sum_t k_sm*v over 64-t chunk ----
__global__ __launch_bounds__(256) void context_kernel(const float* __restrict__ qkv,
                                                      float* __restrict__ ctx_part) {
  const int n = blockIdx.y, chunk = blockIdx.x;
  const int b = n >> 3, h = n & 7;
  const float* kbase = qkv + (size_t)(512 + h * 64) * 8192 + b * 1024 + chunk * 64;
  const float* vbase = qkv + (size_t)(1024 + h * 64) * 8192 + b * 1024 + chunk * 64;
  __shared__ float Ks[64][68];   // [t][d]
  __shared__ float Vs[64][68];   // [t][e]
  const int tid = threadIdx.x;
  const int dr = tid >> 2;            // row 0..63
  const int tq = (tid & 3) * 16;      // t offset
#pragma unroll
  for (int i = 0; i < 16; i += 4) {
    float4 kf = *(const float4*)(kbase + (size_t)dr * 8192 + tq + i);
    float4 vf = *(const float4*)(vbase + (size_t)dr * 8192 + tq + i);
    Ks[tq+i+0][dr] = kf.x; Ks[tq+i+1][dr] = kf.y; Ks[tq+i+2][dr] = kf.z; Ks[tq+i+3][dr] = kf.w;
    Vs[tq+i+0][dr] = vf.x; Vs[tq+i+1][dr] = vf.y; Vs[tq+i+2][dr] = vf.z; Vs[tq+i+3][dr] = vf.w;
  }
  __syncthreads();
  const int d0 = (tid & 15) * 4, e0 = (tid >> 4) * 4;
  float acc[4][4] = {{0.f}};
  for (int t = 0; t < 64; ++t) {
    float4 kv = *(const float4*)&Ks[t][d0];
    float4 vv = *(const float4*)&Vs[t][e0];
    float ka[4] = {kv.x, kv.y, kv.z, kv.w};
    float va[4] = {vv.x, vv.y, vv.z, vv.w};
#pragma unroll
    for (int a = 0; a < 4; ++a)
#pragma unroll
      for (int c = 0; c < 4; ++c)
        acc[a][c] = fmaf(ka[a], va[c], acc[a][c]);
  }
  float* outp = ctx_part + ((size_t)chunk * 64 + n) * 4096;
#pragma unroll
  for (int a = 0; a < 4; ++a)
#pragma unroll
    for (int c = 0; c < 4; ++c)
      outp[(d0 + a) * 64 + e0 + c] = acc[a][c];
}

__global__ __launch_bounds__(256) void reduce_ctx(const float* __restrict__ part,
                                                  float* __restrict__ ctx) {
  const int idx = blockIdx.x * 256 + threadIdx.x;
  float s = 0.f;
#pragma unroll
  for (int c = 0; c < 16; ++c) s += part[(size_t)c * 262144 + idx];
  ctx[idx] = s;
}

// ---------------- content[n,e,t] = sum_d ctx[n,d,e]*q[n,d,t] ----------------
__global__ __launch_bounds__(256) void content_kernel(const float* __restrict__ qkv,
                                                      const float* __restrict__ ctx,
                                                      float* __restrict__ content) {
  const int n = blockIdx.y, chunk = blockIdx.x;   // 16 chunks of 64 t
  const int b = n >> 3, h = n & 7;
  __shared__ float cs[4096];
  const float* cp = ctx + (size_t)n * 4096;
  for (int i = threadIdx.x * 4; i < 4096; i += 1024)
    *(float4*)&cs[i] = *(const float4*)&cp[i];
  __syncthreads();
  const int tid = threadIdx.x;
  const int e0 = (tid & 15) * 4;
  const int t0 = chunk * 64 + (tid >> 4) * 4;
  const float* qbase = qkv + (size_t)(h * 64) * 8192 + b * 1024 + t0;
  float acc[4][4] = {{0.f}};
  for (int d = 0; d < 64; ++d) {
    float4 cv = *(const float4*)&cs[d * 64 + e0];
    float4 qv = *(const float4*)(qbase + (size_t)d * 8192);
    float ca[4] = {cv.x, cv.y, cv.z, cv.w};
    float qa[4] = {qv.x, qv.y, qv.z, qv.w};
#pragma unroll
    for (int a = 0; a < 4; ++a)
#pragma unroll
      for (int c = 0; c < 4; ++c)
        acc[a][c] = fmaf(ca[a], qa[c], acc[a][c]);
  }
  float* op = content + ((size_t)n * 64 + e0) * 1024 + t0;
#pragma unroll
  for (int a = 0; a < 4; ++a) {
    float4 r = {acc[a][0], acc[a][1], acc[a][2], acc[a][3]};
    *(float4*)(op + (size_t)a * 1024) = r;
  }
}

// ---------------- S[n,t] = sum_d q[n,d,t]*PsumT[d][t]; channel sums of rel = v*S ----------------
__global__ __launch_bounds__(256) void stats_kernel(const float* __restrict__ qkv,
                                                    const float* __restrict__ PsumT,
                                                    float* __restrict__ S,
                                                    float* __restrict__ sums,
                                                    float* __restrict__ sumsq) {
  const int n = blockIdx.x;
  const int b = n >> 3, h = n & 7;
  __shared__ float s_lds[1024];
  const int tid = threadIdx.x;
  const int t0 = tid * 4;
  const float* qbase = qkv + (size_t)(h * 64) * 8192 + b * 1024;
  float4 acc = {0.f, 0.f, 0.f, 0.f};
  for (int d = 0; d < 64; ++d) {
    float4 qv = *(const float4*)(qbase + (size_t)d * 8192 + t0);
    float4 pv = *(const float4*)(PsumT + d * 1024 + t0);
    acc.x = fmaf(qv.x, pv.x, acc.x);
    acc.y = fmaf(qv.y, pv.y, acc.y);
    acc.z = fmaf(qv.z, pv.z, acc.z);
    acc.w = fmaf(qv.w, pv.w, acc.w);
  }
  *(float4*)&s_lds[t0] = acc;
  *(float4*)(S + (size_t)n * 1024 + t0) = acc;
  __syncthreads();
  const int w = tid >> 6, lane = tid & 63;
  const float* vbase = qkv + (size_t)(1024 + h * 64) * 8192 + b * 1024;
  for (int ei = 0; ei < 16; ++ei) {
    const int e = w + ei * 4;
    const float* vr = vbase + (size_t)e * 8192;
    float a1 = 0.f, a2 = 0.f;
#pragma unroll
    for (int it = 0; it < 16; ++it) {
      int t = lane + it * 64;
      float val = vr[t] * s_lds[t];
      a1 += val;
      a2 = fmaf(val, val, a2);
    }
#pragma unroll
    for (int off = 32; off; off >>= 1) {
      a1 += __shfl_down(a1, off);
      a2 += __shfl_down(a2, off);
    }
    if (lane == 0) {
      atomicAdd(&sums[e], a1);
      atomicAdd(&sumsq[e], a2);
    }
  }
}

__global__ void bn_final(const float* __restrict__ sums, const float* __restrict__ sumsq,
                         const float* __restrict__ gamma, const float* __restrict__ beta,
                         float* __restrict__ scale, float* __restrict__ shift) {
  const int e = threadIdx.x;
  const float cnt = 65536.0f;
  float mu = sums[e] / cnt;
  float var = sumsq[e] / cnt - mu * mu;
  float sc = gamma[e] * rsqrtf(var + 1e-5f);
  scale[e] = sc;
  shift[e] = beta[e] - mu * sc;
}

// ---------------- out (in-place on content): content += BN(v*S) ----------------
__global__ __launch_bounds__(256) void out_build(float* __restrict__ content,
                                                 const float* __restrict__ qkv,
                                                 const float* __restrict__ S,
                                                 const float* __restrict__ scale,
                                                 const float* __restrict__ shift) {
  const size_t id = (size_t)blockIdx.x * 256 + threadIdx.x;  // 1,048,576 float4s
  const int t4 = (int)(id & 255);
  const int e = (int)((id >> 8) & 63);
  const int n = (int)(id >> 14);
  const int b = n >> 3, h = n & 7;
  const size_t ci = (((size_t)n * 64 + e) * 1024) + t4 * 4;
  float4 c = *(const float4*)&content[ci];
  float4 v = *(const float4*)(qkv + (size_t)(1024 + h * 64 + e) * 8192 + b * 1024 + t4 * 4);
  float4 s = *(const float4*)(S + (size_t)n * 1024 + t4 * 4);
  const float sc = scale[e], sh = shift[e];
  c.x = fmaf(v.x * s.x, sc, c.x + sh);
  c.y = fmaf(v.y * s.y, sc, c.y + sh);
  c.z = fmaf(v.z * s.z, sc, c.z + sh);
  c.w = fmaf(v.w * s.w, sc, c.w + sh);
  *(float4*)&content[ci] = c;
}

extern "C" void kernel_launch(void* const* d_in, const int* in_sizes, int n_in,
                              void* d_out, int out_size, void* d_ws, size_t ws_size,
                              hipStream_t stream) {
  const float* x       = (const float*)d_in[0];   // (8,1024,512)
  const float* Wqkv    = (const float*)d_in[1];   // (1536,512)
  const float* Wout    = (const float*)d_in[2];   // (512,512)
  const float* bout    = (const float*)d_in[3];   // (512)
  const float* relpos  = (const float*)d_in[4];   // (63,64)
  const float* gamma   = (const float*)d_in[5];   // (64)
  const float* beta    = (const float*)d_in[6];   // (64)
  float* out = (float*)d_out;                     // (8,512,1024)

  float* ws = (float*)d_ws;
  float* qkv      = ws;                       // 1536*8192      = 12,582,912
  float* ctx_part = qkv + 12582912;           // 16*64*4096     =  4,194,304
  float* ctx      = ctx_part + 4194304;       // 64*4096        =    262,144
  float* content  = ctx + 262144;             // 64*64*1024     =  4,194,304
  float* PsumT    = content + 4194304;        // 64*1024        =     65,536
  float* S        = PsumT + 65536;            // 64*1024        =     65,536
  float* sums     = S + 65536;                // 64
  float* sumsq    = sums + 64;                // 64
  float* scale    = sumsq + 64;               // 64
  float* shift    = scale + 64;               // 64

  // 1. qkv = Wqkv (1536x512) @ x^T (8192x512)^T  -> [1536][8192]
  gemm_nt<<<dim3(64, 12), 256, 0, stream>>>(Wqkv, x, qkv, 1536, 8192, 512);
  // 2. softmax over t for k rows (in place)
  softmax_k<<<4096, 256, 0, stream>>>(qkv);
  // 3. PsumT
  psum_kernel<<<dim3(4, 64), 256, 0, stream>>>(relpos, PsumT);
  // 4. context partials + reduce
  context_kernel<<<dim3(16, 64), 256, 0, stream>>>(qkv, ctx_part);
  reduce_ctx<<<1024, 256, 0, stream>>>(ctx_part, ctx);
  // 5. content_out
  content_kernel<<<dim3(16, 64), 256, 0, stream>>>(qkv, ctx, content);
  // 6. S + BN stats
  hipMemsetAsync(sums, 0, 2 * 64 * sizeof(float), stream);
  stats_kernel<<<64, 256, 0, stream>>>(qkv, PsumT, S, sums, sumsq);
  bn_final<<<1, 64, 0, stream>>>(sums, sumsq, gamma, beta, scale, shift);
  // 7. out = content + BN(v*S)   (in place on content; layout == (B, DH, T))
  out_build<<<4096, 256, 0, stream>>>(content, qkv, S, scale, shift);
  // 8. final: out = Wout @ out + bout
  gemm_nn_bias<<<dim3(64, 4), 256, 0, stream>>>(Wout, content, bout, out);
}

// Round 2
// 303.457 us; speedup vs baseline: 1.3837x; 1.3837x over previous
//
#include <hip/hip_runtime.h>
#include <hip/hip_bf16.h>

// Problem constants: B=8, T=1024, DIM=512, H=8, DK=64, L=32, DH=512, DOUT=512
// qkv buffer layout: [1536][8192], row o = {q:0..511, k:512..1023, v:1024..1535},
// col = b*1024 + t.  n = b*8 + h; row for (q,h,d) = h*64+d.

typedef short bf16x8 __attribute__((ext_vector_type(8)));
typedef float f32x4 __attribute__((ext_vector_type(4)));

static __device__ __forceinline__ unsigned short f2bf(float f) {
  __hip_bfloat16 h = __float2bfloat16(f);
  return *reinterpret_cast<unsigned short*>(&h);
}

// ---------------- cast x (fp32) -> xb (bf16), 1,048,576 float4s ----------------
__global__ __launch_bounds__(256) void cast_x(const float* __restrict__ src,
                                              unsigned short* __restrict__ dst) {
  const int i = blockIdx.x * 256 + threadIdx.x;
  float4 v = ((const float4*)src)[i];
  ushort4 o = {f2bf(v.x), f2bf(v.y), f2bf(v.z), f2bf(v.w)};
  ((ushort4*)dst)[i] = o;
}

// ---------------- bf16 MFMA GEMM NT: qkv[1536][8192] = Wqkv(f32,cvt) @ xb^T ----------------
__global__ __launch_bounds__(256) void gemm_qkv(const float* __restrict__ A,
                                                const unsigned short* __restrict__ B,
                                                float* __restrict__ C) {
  __shared__ alignas(16) unsigned short As[128][40];
  __shared__ alignas(16) unsigned short Bs[128][40];
  const int tid = threadIdx.x;
  const int bm = blockIdx.y * 128, bn = blockIdx.x * 128;
  const int r = tid >> 1;
  const int kc = (tid & 1) * 16;
  const float* Ap = A + (size_t)(bm + r) * 512 + kc;
  const unsigned short* Bp = B + (size_t)(bn + r) * 512 + kc;
  const int wave = tid >> 6, lane = tid & 63;
  const int wm = (wave >> 1) * 64, wn = (wave & 1) * 64;
  const int fr = lane & 15, fk = (lane >> 4) * 8;
  f32x4 acc[4][4];
#pragma unroll
  for (int i = 0; i < 4; ++i)
#pragma unroll
    for (int j = 0; j < 4; ++j) acc[i][j] = (f32x4){0.f, 0.f, 0.f, 0.f};
  for (int k0 = 0; k0 < 512; k0 += 32) {
    float4 a0 = *(const float4*)(Ap + k0);
    float4 a1 = *(const float4*)(Ap + k0 + 4);
    float4 a2 = *(const float4*)(Ap + k0 + 8);
    float4 a3 = *(const float4*)(Ap + k0 + 12);
    uint4 b0 = *(const uint4*)(Bp + k0);
    uint4 b1 = *(const uint4*)(Bp + k0 + 8);
    ushort4 p0 = {f2bf(a0.x), f2bf(a0.y), f2bf(a0.z), f2bf(a0.w)};
    ushort4 p1 = {f2bf(a1.x), f2bf(a1.y), f2bf(a1.z), f2bf(a1.w)};
    ushort4 p2 = {f2bf(a2.x), f2bf(a2.y), f2bf(a2.z), f2bf(a2.w)};
    ushort4 p3 = {f2bf(a3.x), f2bf(a3.y), f2bf(a3.z), f2bf(a3.w)};
    __syncthreads();
    *(ushort4*)&As[r][kc] = p0;
    *(ushort4*)&As[r][kc + 4] = p1;
    *(ushort4*)&As[r][kc + 8] = p2;
    *(ushort4*)&As[r][kc + 12] = p3;
    *(uint4*)&Bs[r][kc] = b0;
    *(uint4*)&Bs[r][kc + 8] = b1;
    __syncthreads();
    bf16x8 af[4], bq[4];
#pragma unroll
    for (int mi = 0; mi < 4; ++mi) af[mi] = *(bf16x8*)&As[wm + mi * 16 + fr][fk];
#pragma unroll
    for (int nj = 0; nj < 4; ++nj) bq[nj] = *(bf16x8*)&Bs[wn + nj * 16 + fr][fk];
#pragma unroll
    for (int mi = 0; mi < 4; ++mi)
#pragma unroll
      for (int nj = 0; nj < 4; ++nj)
        acc[mi][nj] = __builtin_amdgcn_mfma_f32_16x16x32_bf16(af[mi], bq[nj], acc[mi][nj], 0, 0, 0);
  }
#pragma unroll
  for (int mi = 0; mi < 4; ++mi) {
    const int row0 = bm + wm + mi * 16 + (lane >> 4) * 4;
#pragma unroll
    for (int nj = 0; nj < 4; ++nj) {
      const int col = bn + wn + nj * 16 + fr;
#pragma unroll
      for (int rr = 0; rr < 4; ++rr)
        C[(size_t)(row0 + rr) * 8192 + col] = acc[mi][nj][rr];
    }
  }
}

// ---------------- bf16 MFMA GEMM NT + bias + remap: out[b][o][t] ----------------
__global__ __launch_bounds__(256) void gemm_out(const float* __restrict__ A,      // Wout fp32 [512][512]
                                                const unsigned short* __restrict__ B, // outT bf16 [8192][512]
                                                const float* __restrict__ bias,
                                                float* __restrict__ out) {
  __shared__ alignas(16) unsigned short As[128][40];
  __shared__ alignas(16) unsigned short Bs[128][40];
  const int tid = threadIdx.x;
  const int bm = blockIdx.y * 128, bn = blockIdx.x * 128;
  const int r = tid >> 1;
  const int kc = (tid & 1) * 16;
  const float* Ap = A + (size_t)(bm + r) * 512 + kc;
  const unsigned short* Bp = B + (size_t)(bn + r) * 512 + kc;
  const int wave = tid >> 6, lane = tid & 63;
  const int wm = (wave >> 1) * 64, wn = (wave & 1) * 64;
  const int fr = lane & 15, fk = (lane >> 4) * 8;
  f32x4 acc[4][4];
#pragma unroll
  for (int i = 0; i < 4; ++i)
#pragma unroll
    for (int j = 0; j < 4; ++j) acc[i][j] = (f32x4){0.f, 0.f, 0.f, 0.f};
  for (int k0 = 0; k0 < 512; k0 += 32) {
    float4 a0 = *(const float4*)(Ap + k0);
    float4 a1 = *(const float4*)(Ap + k0 + 4);
    float4 a2 = *(const float4*)(Ap + k0 + 8);
    float4 a3 = *(const float4*)(Ap + k0 + 12);
    uint4 b0 = *(const uint4*)(Bp + k0);
    uint4 b1 = *(const uint4*)(Bp + k0 + 8);
    ushort4 p0 = {f2bf(a0.x), f2bf(a0.y), f2bf(a0.z), f2bf(a0.w)};
    ushort4 p1 = {f2bf(a1.x), f2bf(a1.y), f2bf(a1.z), f2bf(a1.w)};
    ushort4 p2 = {f2bf(a2.x), f2bf(a2.y), f2bf(a2.z), f2bf(a2.w)};
    ushort4 p3 = {f2bf(a3.x), f2bf(a3.y), f2bf(a3.z), f2bf(a3.w)};
    __syncthreads();
    *(ushort4*)&As[r][kc] = p0;
    *(ushort4*)&As[r][kc + 4] = p1;
    *(ushort4*)&As[r][kc + 8] = p2;
    *(ushort4*)&As[r][kc + 12] = p3;
    *(uint4*)&Bs[r][kc] = b0;
    *(uint4*)&Bs[r][kc + 8] = b1;
    __syncthreads();
    bf16x8 af[4], bq[4];
#pragma unroll
    for (int mi = 0; mi < 4; ++mi) af[mi] = *(bf16x8*)&As[wm + mi * 16 + fr][fk];
#pragma unroll
    for (int nj = 0; nj < 4; ++nj) bq[nj] = *(bf16x8*)&Bs[wn + nj * 16 + fr][fk];
#pragma unroll
    for (int mi = 0; mi < 4; ++mi)
#pragma unroll
      for (int nj = 0; nj < 4; ++nj)
        acc[mi][nj] = __builtin_amdgcn_mfma_f32_16x16x32_bf16(af[mi], bq[nj], acc[mi][nj], 0, 0, 0);
  }
#pragma unroll
  for (int mi = 0; mi < 4; ++mi) {
    const int row0 = bm + wm + mi * 16 + (lane >> 4) * 4;
#pragma unroll
    for (int nj = 0; nj < 4; ++nj) {
      const int col = bn + wn + nj * 16 + fr;   // g = b*1024 + t
      const int b = col >> 10, t = col & 1023;
#pragma unroll
      for (int rr = 0; rr < 4; ++rr)
        out[(size_t)b * 524288 + (size_t)(row0 + rr) * 1024 + t] = acc[mi][nj][rr] + bias[row0 + rr];
    }
  }
}

// ---------------- softmax over t for each k row ----------------
__global__ __launch_bounds__(256) void softmax_k(float* __restrict__ qkv) {
  const int rI = blockIdx.x;          // 0..4095
  const int hd = rI >> 3, b = rI & 7;
  float* row = qkv + (size_t)(512 + hd) * 8192 + b * 1024;
  const int tid = threadIdx.x;
  float4 x = *(const float4*)(row + tid * 4);
  float m = fmaxf(fmaxf(x.x, x.y), fmaxf(x.z, x.w));
#pragma unroll
  for (int off = 32; off; off >>= 1) m = fmaxf(m, __shfl_down(m, off));
  __shared__ float red1[4];
  __shared__ float red2[4];
  const int w = tid >> 6, lane = tid & 63;
  if (lane == 0) red1[w] = m;
  __syncthreads();
  m = fmaxf(fmaxf(red1[0], red1[1]), fmaxf(red1[2], red1[3]));
  float4 e;
  e.x = __expf(x.x - m); e.y = __expf(x.y - m); e.z = __expf(x.z - m); e.w = __expf(x.w - m);
  float s = e.x + e.y + e.z + e.w;
#pragma unroll
  for (int off = 32; off; off >>= 1) s += __shfl_down(s, off);
  if (lane == 0) red2[w] = s;
  __syncthreads();
  float inv = 1.0f / (red2[0] + red2[1] + red2[2] + red2[3]);
  e.x *= inv; e.y *= inv; e.z *= inv; e.w *= inv;
  *(float4*)(row + tid * 4) = e;
}

// ---------------- PsumT[d][t] ----------------
__global__ __launch_bounds__(256) void psum_kernel(const float* __restrict__ relpos,
                                                   float* __restrict__ PsumT) {
  const int d = blockIdx.y;
  const int t = blockIdx.x * 256 + threadIdx.x;
  float acc = 0.f;
  for (int j = 0; j < 63; ++j) {
    int i = t + j - 31;
    float v = relpos[j * 64 + d];
    if (i >= 0 && i < 1024) acc += v;
  }
  PsumT[d * 1024 + t] = acc;
}

// ---------------- context partials ----------------
__global__ __launch_bounds__(256) void context_kernel(const float* __restrict__ qkv,
                                                      float* __restrict__ ctx_part) {
  const int n = blockIdx.y, chunk = blockIdx.x;
  const int b = n >> 3, h = n & 7;
  const float* kbase = qkv + (size_t)(512 + h * 64) * 8192 + b * 1024 + chunk * 64;
  const float* vbase = qkv + (size_t)(1024 + h * 64) * 8192 + b * 1024 + chunk * 64;
  __shared__ float Ks[64][68];
  __shared__ float Vs[64][68];
  const int tid = threadIdx.x;
  const int dr = tid >> 2;
  const int tq = (tid & 3) * 16;
#pragma unroll
  for (int i = 0; i < 16; i += 4) {
    float4 kf = *(const float4*)(kbase + (size_t)dr * 8192 + tq + i);
    float4 vf = *(const float4*)(vbase + (size_t)dr * 8192 + tq + i);
    Ks[tq+i+0][dr] = kf.x; Ks[tq+i+1][dr] = kf.y; Ks[tq+i+2][dr] = kf.z; Ks[tq+i+3][dr] = kf.w;
    Vs[tq+i+0][dr] = vf.x; Vs[tq+i+1][dr] = vf.y; Vs[tq+i+2][dr] = vf.z; Vs[tq+i+3][dr] = vf.w;
  }
  __syncthreads();
  const int d0 = (tid & 15) * 4, e0 = (tid >> 4) * 4;
  float acc[4][4] = {{0.f}};
  for (int t = 0; t < 64; ++t) {
    float4 kv = *(const float4*)&Ks[t][d0];
    float4 vv = *(const float4*)&Vs[t][e0];
    float ka[4] = {kv.x, kv.y, kv.z, kv.w};
    float va[4] = {vv.x, vv.y, vv.z, vv.w};
#pragma unroll
    for (int a = 0; a < 4; ++a)
#pragma unroll
      for (int c = 0; c < 4; ++c)
        acc[a][c] = fmaf(ka[a], va[c], acc[a][c]);
  }
  float* outp = ctx_part + ((size_t)chunk * 64 + n) * 4096;
#pragma unroll
  for (int a = 0; a < 4; ++a)
#pragma unroll
    for (int c = 0; c < 4; ++c)
      outp[(d0 + a) * 64 + e0 + c] = acc[a][c];
}

__global__ __launch_bounds__(256) void reduce_ctx(const float* __restrict__ part,
                                                  float* __restrict__ ctx) {
  const int idx = blockIdx.x * 256 + threadIdx.x;
  float s = 0.f;
#pragma unroll
  for (int c = 0; c < 16; ++c) s += part[(size_t)c * 262144 + idx];
  ctx[idx] = s;
}

// ---------------- content[n,e,t] = sum_d ctx[n,d,e]*q[n,d,t] ----------------
__global__ __launch_bounds__(256) void content_kernel(const float* __restrict__ qkv,
                                                      const float* __restrict__ ctx,
                                                      float* __restrict__ content) {
  const int n = blockIdx.y, chunk = blockIdx.x;
  const int b = n >> 3, h = n & 7;
  __shared__ float cs[4096];
  const float* cp = ctx + (size_t)n * 4096;
  for (int i = threadIdx.x * 4; i < 4096; i += 1024)
    *(float4*)&cs[i] = *(const float4*)&cp[i];
  __syncthreads();
  const int tid = threadIdx.x;
  const int e0 = (tid & 15) * 4;
  const int t0 = chunk * 64 + (tid >> 4) * 4;
  const float* qbase = qkv + (size_t)(h * 64) * 8192 + b * 1024 + t0;
  float acc[4][4] = {{0.f}};
  for (int d = 0; d < 64; ++d) {
    float4 cv = *(const float4*)&cs[d * 64 + e0];
    float4 qv = *(const float4*)(qbase + (size_t)d * 8192);
    float ca[4] = {cv.x, cv.y, cv.z, cv.w};
    float qa[4] = {qv.x, qv.y, qv.z, qv.w};
#pragma unroll
    for (int a = 0; a < 4; ++a)
#pragma unroll
      for (int c = 0; c < 4; ++c)
        acc[a][c] = fmaf(ca[a], qa[c], acc[a][c]);
  }
  float* op = content + ((size_t)n * 64 + e0) * 1024 + t0;
#pragma unroll
  for (int a = 0; a < 4; ++a) {
    float4 rv = {acc[a][0], acc[a][1], acc[a][2], acc[a][3]};
    *(float4*)(op + (size_t)a * 1024) = rv;
  }
}

// ---------------- S + BN stats (grid 4 x 64) ----------------
__global__ __launch_bounds__(256) void stats_kernel(const float* __restrict__ qkv,
                                                    const float* __restrict__ PsumT,
                                                    float* __restrict__ S,
                                                    float* __restrict__ sums,
                                                    float* __restrict__ sumsq) {
  const int n = blockIdx.y, tc = blockIdx.x;
  const int b = n >> 3, h = n & 7;
  const int t0 = tc * 256;
  const int tid = threadIdx.x;
  const int t = t0 + tid;
  __shared__ float s_lds[256];
  const float* qbase = qkv + (size_t)(h * 64) * 8192 + b * 1024;
  float acc = 0.f;
  for (int d = 0; d < 64; ++d)
    acc = fmaf(qbase[(size_t)d * 8192 + t], PsumT[d * 1024 + t], acc);
  s_lds[tid] = acc;
  S[(size_t)n * 1024 + t] = acc;
  __syncthreads();
  const int w = tid >> 6, lane = tid & 63;
  const float* vbase = qkv + (size_t)(1024 + h * 64) * 8192 + b * 1024 + t0;
  for (int ei = 0; ei < 16; ++ei) {
    const int e = w * 16 + ei;
    const float* vr = vbase + (size_t)e * 8192;
    float a1 = 0.f, a2 = 0.f;
#pragma unroll
    for (int it = 0; it < 4; ++it) {
      int idx = lane + it * 64;
      float val = vr[idx] * s_lds[idx];
      a1 += val;
      a2 = fmaf(val, val, a2);
    }
#pragma unroll
    for (int off = 32; off; off >>= 1) {
      a1 += __shfl_down(a1, off);
      a2 += __shfl_down(a2, off);
    }
    if (lane == 0) {
      atomicAdd(&sums[e], a1);
      atomicAdd(&sumsq[e], a2);
    }
  }
}

__global__ void bn_final(const float* __restrict__ sums, const float* __restrict__ sumsq,
                         const float* __restrict__ gamma, const float* __restrict__ beta,
                         float* __restrict__ scale, float* __restrict__ shift) {
  const int e = threadIdx.x;
  const float cnt = 65536.0f;
  float mu = sums[e] / cnt;
  float var = sumsq[e] / cnt - mu * mu;
  float sc = gamma[e] * rsqrtf(var + 1e-5f);
  scale[e] = sc;
  shift[e] = beta[e] - mu * sc;
}

// ---------------- out_build: combined = content + BN(v*S); write transposed bf16 ----------------
__global__ __launch_bounds__(256) void out_build_t(const float* __restrict__ content,
                                                   const float* __restrict__ qkv,
                                                   const float* __restrict__ S,
                                                   const float* __restrict__ scale,
                                                   const float* __restrict__ shift,
                                                   unsigned short* __restrict__ outT) {
  const int n = blockIdx.y, tc = blockIdx.x;   // grid (16, 64)
  const int b = n >> 3, h = n & 7;
  const int t0 = tc * 64;
  __shared__ alignas(16) unsigned short T[64][72];
  const int tid = threadIdx.x;
  const int e = tid >> 2, tq = (tid & 3) * 16;
  const float sc = scale[e], sh = shift[e];
  const float* cp = content + ((size_t)n * 64 + e) * 1024 + t0 + tq;
  const float* vp = qkv + (size_t)(1024 + h * 64 + e) * 8192 + b * 1024 + t0 + tq;
  const float* sp = S + (size_t)n * 1024 + t0 + tq;
#pragma unroll
  for (int i0 = 0; i0 < 16; i0 += 4) {
    float4 c = *(const float4*)(cp + i0);
    float4 v = *(const float4*)(vp + i0);
    float4 s = *(const float4*)(sp + i0);
    T[tq + i0 + 0][e] = f2bf(fmaf(v.x * s.x, sc, c.x + sh));
    T[tq + i0 + 1][e] = f2bf(fmaf(v.y * s.y, sc, c.y + sh));
    T[tq + i0 + 2][e] = f2bf(fmaf(v.z * s.z, sc, c.z + sh));
    T[tq + i0 + 3][e] = f2bf(fmaf(v.w * s.w, sc, c.w + sh));
  }
  __syncthreads();
  const int tl = tid >> 2, dq = (tid & 3) * 16;
  uint4 r0 = *(uint4*)&T[tl][dq];
  uint4 r1 = *(uint4*)&T[tl][dq + 8];
  unsigned short* op = outT + ((size_t)(b * 1024 + t0 + tl)) * 512 + h * 64 + dq;
  *(uint4*)op = r0;
  *(uint4*)(op + 8) = r1;
}

extern "C" void kernel_launch(void* const* d_in, const int* in_sizes, int n_in,
                              void* d_out, int out_size, void* d_ws, size_t ws_size,
                              hipStream_t stream) {
  const float* x       = (const float*)d_in[0];   // (8,1024,512)
  const float* Wqkv    = (const float*)d_in[1];   // (1536,512)
  const float* Wout    = (const float*)d_in[2];   // (512,512)
  const float* bout    = (const float*)d_in[3];   // (512)
  const float* relpos  = (const float*)d_in[4];   // (63,64)
  const float* gamma   = (const float*)d_in[5];   // (64)
  const float* beta    = (const float*)d_in[6];   // (64)
  float* out = (float*)d_out;                     // (8,512,1024)

  float* ws = (float*)d_ws;
  float* qkv      = ws;                       // 1536*8192 = 12,582,912 floats
  float* R        = qkv + 12582912;           // overlay region: 4,194,304 floats
  unsigned short* xb   = (unsigned short*)R;  // xb bf16 [8192][512]  (early life)
  unsigned short* outT = (unsigned short*)R;  // outT bf16 [8192][512] (late life)
  float* ctx_part = R;                        // 16*64*4096 floats    (mid life)
  float* ctx      = R + 4194304;              // 64*4096 = 262,144
  float* content  = ctx + 262144;             // 64*64*1024 = 4,194,304
  float* PsumT    = content + 4194304;        // 65,536
  float* S        = PsumT + 65536;            // 65,536
  float* sums     = S + 65536;                // 64
  float* sumsq    = sums + 64;                // 64
  float* scale    = sumsq + 64;               // 64
  float* shift    = scale + 64;               // 64

  // 1. cast x -> bf16
  cast_x<<<4096, 256, 0, stream>>>(x, xb);
  // 2. qkv = Wqkv @ x^T via bf16 MFMA
  gemm_qkv<<<dim3(64, 12), 256, 0, stream>>>(Wqkv, xb, qkv);
  // 3. softmax over t for k rows (in place)
  softmax_k<<<4096, 256, 0, stream>>>(qkv);
  // 4. PsumT
  psum_kernel<<<dim3(4, 64), 256, 0, stream>>>(relpos, PsumT);
  // 5. context partials + reduce (clobbers xb — dead)
  context_kernel<<<dim3(16, 64), 256, 0, stream>>>(qkv, ctx_part);
  reduce_ctx<<<1024, 256, 0, stream>>>(ctx_part, ctx);
  // 6. content_out
  content_kernel<<<dim3(16, 64), 256, 0, stream>>>(qkv, ctx, content);
  // 7. S + BN stats
  hipMemsetAsync(sums, 0, 2 * 64 * sizeof(float), stream);
  stats_kernel<<<dim3(4, 64), 256, 0, stream>>>(qkv, PsumT, S, sums, sumsq);
  bn_final<<<1, 64, 0, stream>>>(sums, sumsq, gamma, beta, scale, shift);
  // 8. combined out, transposed bf16 (clobbers ctx_part — dead)
  out_build_t<<<dim3(16, 64), 256, 0, stream>>>(content, qkv, S, scale, shift, outT);
  // 9. final GEMM: out = Wout @ comb + bout via bf16 MFMA
  gemm_out<<<dim3(64, 4), 256, 0, stream>>>(Wout, outT, bout, out);
}

// Round 3
// 220.139 us; speedup vs baseline: 1.9073x; 1.3785x over previous
//
#include <hip/hip_runtime.h>
#include <hip/hip_bf16.h>

// Problem constants: B=8, T=1024, DIM=512, H=8, DK=64, L=32, DH=512, DOUT=512
// qkv buffer layout: [1536][8192], row o = {q:0..511, k:512..1023, v:1024..1535},
// col = b*1024 + t.  n = b*8 + h; row for (q,h,d) = h*64+d.

typedef short bf16x8 __attribute__((ext_vector_type(8)));
typedef float f32x4 __attribute__((ext_vector_type(4)));

static __device__ __forceinline__ unsigned short f2bf(float f) {
  __hip_bfloat16 h = __float2bfloat16(f);
  return *reinterpret_cast<unsigned short*>(&h);
}

// ---------------- cast x (fp32) -> xb (bf16) ----------------
__global__ __launch_bounds__(256) void cast_x(const float* __restrict__ src,
                                              unsigned short* __restrict__ dst) {
  const int i = blockIdx.x * 256 + threadIdx.x;
  float4 v = ((const float4*)src)[i];
  ushort4 o = {f2bf(v.x), f2bf(v.y), f2bf(v.z), f2bf(v.w)};
  ((ushort4*)dst)[i] = o;
}

// ---------------- bf16 MFMA GEMM NT: qkv[1536][8192] = Wqkv(f32,cvt) @ xb^T ----------------
__global__ __launch_bounds__(256) void gemm_qkv(const float* __restrict__ A,
                                                const unsigned short* __restrict__ B,
                                                float* __restrict__ C) {
  __shared__ alignas(16) unsigned short As[128][40];
  __shared__ alignas(16) unsigned short Bs[128][40];
  const int tid = threadIdx.x;
  const int bm = blockIdx.y * 128, bn = blockIdx.x * 128;
  const int r = tid >> 1;
  const int kc = (tid & 1) * 16;
  const float* Ap = A + (size_t)(bm + r) * 512 + kc;
  const unsigned short* Bp = B + (size_t)(bn + r) * 512 + kc;
  const int wave = tid >> 6, lane = tid & 63;
  const int wm = (wave >> 1) * 64, wn = (wave & 1) * 64;
  const int fr = lane & 15, fk = (lane >> 4) * 8;
  f32x4 acc[4][4];
#pragma unroll
  for (int i = 0; i < 4; ++i)
#pragma unroll
    for (int j = 0; j < 4; ++j) acc[i][j] = (f32x4){0.f, 0.f, 0.f, 0.f};
  for (int k0 = 0; k0 < 512; k0 += 32) {
    float4 a0 = *(const float4*)(Ap + k0);
    float4 a1 = *(const float4*)(Ap + k0 + 4);
    float4 a2 = *(const float4*)(Ap + k0 + 8);
    float4 a3 = *(const float4*)(Ap + k0 + 12);
    uint4 b0 = *(const uint4*)(Bp + k0);
    uint4 b1 = *(const uint4*)(Bp + k0 + 8);
    ushort4 p0 = {f2bf(a0.x), f2bf(a0.y), f2bf(a0.z), f2bf(a0.w)};
    ushort4 p1 = {f2bf(a1.x), f2bf(a1.y), f2bf(a1.z), f2bf(a1.w)};
    ushort4 p2 = {f2bf(a2.x), f2bf(a2.y), f2bf(a2.z), f2bf(a2.w)};
    ushort4 p3 = {f2bf(a3.x), f2bf(a3.y), f2bf(a3.z), f2bf(a3.w)};
    __syncthreads();
    *(ushort4*)&As[r][kc] = p0;
    *(ushort4*)&As[r][kc + 4] = p1;
    *(ushort4*)&As[r][kc + 8] = p2;
    *(ushort4*)&As[r][kc + 12] = p3;
    *(uint4*)&Bs[r][kc] = b0;
    *(uint4*)&Bs[r][kc + 8] = b1;
    __syncthreads();
    bf16x8 af[4], bq[4];
#pragma unroll
    for (int mi = 0; mi < 4; ++mi) af[mi] = *(bf16x8*)&As[wm + mi * 16 + fr][fk];
#pragma unroll
    for (int nj = 0; nj < 4; ++nj) bq[nj] = *(bf16x8*)&Bs[wn + nj * 16 + fr][fk];
#pragma unroll
    for (int mi = 0; mi < 4; ++mi)
#pragma unroll
      for (int nj = 0; nj < 4; ++nj)
        acc[mi][nj] = __builtin_amdgcn_mfma_f32_16x16x32_bf16(af[mi], bq[nj], acc[mi][nj], 0, 0, 0);
  }
#pragma unroll
  for (int mi = 0; mi < 4; ++mi) {
    const int row0 = bm + wm + mi * 16 + (lane >> 4) * 4;
#pragma unroll
    for (int nj = 0; nj < 4; ++nj) {
      const int col = bn + wn + nj * 16 + fr;
#pragma unroll
      for (int rr = 0; rr < 4; ++rr)
        C[(size_t)(row0 + rr) * 8192 + col] = acc[mi][nj][rr];
    }
  }
}

// ---------------- bf16 MFMA GEMM NT + bias + remap: out[b][o][t] ----------------
__global__ __launch_bounds__(256) void gemm_out(const float* __restrict__ A,
                                                const unsigned short* __restrict__ B,
                                                const float* __restrict__ bias,
                                                float* __restrict__ out) {
  __shared__ alignas(16) unsigned short As[128][40];
  __shared__ alignas(16) unsigned short Bs[128][40];
  const int tid = threadIdx.x;
  const int bm = blockIdx.y * 128, bn = blockIdx.x * 128;
  const int r = tid >> 1;
  const int kc = (tid & 1) * 16;
  const float* Ap = A + (size_t)(bm + r) * 512 + kc;
  const unsigned short* Bp = B + (size_t)(bn + r) * 512 + kc;
  const int wave = tid >> 6, lane = tid & 63;
  const int wm = (wave >> 1) * 64, wn = (wave & 1) * 64;
  const int fr = lane & 15, fk = (lane >> 4) * 8;
  f32x4 acc[4][4];
#pragma unroll
  for (int i = 0; i < 4; ++i)
#pragma unroll
    for (int j = 0; j < 4; ++j) acc[i][j] = (f32x4){0.f, 0.f, 0.f, 0.f};
  for (int k0 = 0; k0 < 512; k0 += 32) {
    float4 a0 = *(const float4*)(Ap + k0);
    float4 a1 = *(const float4*)(Ap + k0 + 4);
    float4 a2 = *(const float4*)(Ap + k0 + 8);
    float4 a3 = *(const float4*)(Ap + k0 + 12);
    uint4 b0 = *(const uint4*)(Bp + k0);
    uint4 b1 = *(const uint4*)(Bp + k0 + 8);
    ushort4 p0 = {f2bf(a0.x), f2bf(a0.y), f2bf(a0.z), f2bf(a0.w)};
    ushort4 p1 = {f2bf(a1.x), f2bf(a1.y), f2bf(a1.z), f2bf(a1.w)};
    ushort4 p2 = {f2bf(a2.x), f2bf(a2.y), f2bf(a2.z), f2bf(a2.w)};
    ushort4 p3 = {f2bf(a3.x), f2bf(a3.y), f2bf(a3.z), f2bf(a3.w)};
    __syncthreads();
    *(ushort4*)&As[r][kc] = p0;
    *(ushort4*)&As[r][kc + 4] = p1;
    *(ushort4*)&As[r][kc + 8] = p2;
    *(ushort4*)&As[r][kc + 12] = p3;
    *(uint4*)&Bs[r][kc] = b0;
    *(uint4*)&Bs[r][kc + 8] = b1;
    __syncthreads();
    bf16x8 af[4], bq[4];
#pragma unroll
    for (int mi = 0; mi < 4; ++mi) af[mi] = *(bf16x8*)&As[wm + mi * 16 + fr][fk];
#pragma unroll
    for (int nj = 0; nj < 4; ++nj) bq[nj] = *(bf16x8*)&Bs[wn + nj * 16 + fr][fk];
#pragma unroll
    for (int mi = 0; mi < 4; ++mi)
#pragma unroll
      for (int nj = 0; nj < 4; ++nj)
        acc[mi][nj] = __builtin_amdgcn_mfma_f32_16x16x32_bf16(af[mi], bq[nj], acc[mi][nj], 0, 0, 0);
  }
#pragma unroll
  for (int mi = 0; mi < 4; ++mi) {
    const int row0 = bm + wm + mi * 16 + (lane >> 4) * 4;
#pragma unroll
    for (int nj = 0; nj < 4; ++nj) {
      const int col = bn + wn + nj * 16 + fr;   // g = b*1024 + t
      const int b = col >> 10, t = col & 1023;
#pragma unroll
      for (int rr = 0; rr < 4; ++rr)
        out[(size_t)b * 524288 + (size_t)(row0 + rr) * 1024 + t] = acc[mi][nj][rr] + bias[row0 + rr];
    }
  }
}

// ---------------- softmax over t for each k row ----------------
__global__ __launch_bounds__(256) void softmax_k(float* __restrict__ qkv) {
  const int rI = blockIdx.x;          // 0..4095
  const int hd = rI >> 3, b = rI & 7;
  float* row = qkv + (size_t)(512 + hd) * 8192 + b * 1024;
  const int tid = threadIdx.x;
  float4 x = *(const float4*)(row + tid * 4);
  float m = fmaxf(fmaxf(x.x, x.y), fmaxf(x.z, x.w));
#pragma unroll
  for (int off = 32; off; off >>= 1) m = fmaxf(m, __shfl_down(m, off));
  __shared__ float red1[4];
  __shared__ float red2[4];
  const int w = tid >> 6, lane = tid & 63;
  if (lane == 0) red1[w] = m;
  __syncthreads();
  m = fmaxf(fmaxf(red1[0], red1[1]), fmaxf(red1[2], red1[3]));
  float4 e;
  e.x = __expf(x.x - m); e.y = __expf(x.y - m); e.z = __expf(x.z - m); e.w = __expf(x.w - m);
  float s = e.x + e.y + e.z + e.w;
#pragma unroll
  for (int off = 32; off; off >>= 1) s += __shfl_down(s, off);
  if (lane == 0) red2[w] = s;
  __syncthreads();
  float inv = 1.0f / (red2[0] + red2[1] + red2[2] + red2[3]);
  e.x *= inv; e.y *= inv; e.z *= inv; e.w *= inv;
  *(float4*)(row + tid * 4) = e;
}

// ---------------- PsumT[d][t] ----------------
__global__ __launch_bounds__(256) void psum_kernel(const float* __restrict__ relpos,
                                                   float* __restrict__ PsumT) {
  const int d = blockIdx.y;
  const int t = blockIdx.x * 256 + threadIdx.x;
  float acc = 0.f;
  for (int j = 0; j < 63; ++j) {
    int i = t + j - 31;
    float v = relpos[j * 64 + d];
    if (i >= 0 && i < 1024) acc += v;
  }
  PsumT[d * 1024 + t] = acc;
}

// ---------------- context partials ----------------
__global__ __launch_bounds__(256) void context_kernel(const float* __restrict__ qkv,
                                                      float* __restrict__ ctx_part) {
  const int n = blockIdx.y, chunk = blockIdx.x;
  const int b = n >> 3, h = n & 7;
  const float* kbase = qkv + (size_t)(512 + h * 64) * 8192 + b * 1024 + chunk * 64;
  const float* vbase = qkv + (size_t)(1024 + h * 64) * 8192 + b * 1024 + chunk * 64;
  __shared__ float Ks[64][68];
  __shared__ float Vs[64][68];
  const int tid = threadIdx.x;
  const int dr = tid >> 2;
  const int tq = (tid & 3) * 16;
#pragma unroll
  for (int i = 0; i < 16; i += 4) {
    float4 kf = *(const float4*)(kbase + (size_t)dr * 8192 + tq + i);
    float4 vf = *(const float4*)(vbase + (size_t)dr * 8192 + tq + i);
    Ks[tq+i+0][dr] = kf.x; Ks[tq+i+1][dr] = kf.y; Ks[tq+i+2][dr] = kf.z; Ks[tq+i+3][dr] = kf.w;
    Vs[tq+i+0][dr] = vf.x; Vs[tq+i+1][dr] = vf.y; Vs[tq+i+2][dr] = vf.z; Vs[tq+i+3][dr] = vf.w;
  }
  __syncthreads();
  const int d0 = (tid & 15) * 4, e0 = (tid >> 4) * 4;
  float acc[4][4] = {{0.f}};
  for (int t = 0; t < 64; ++t) {
    float4 kv = *(const float4*)&Ks[t][d0];
    float4 vv = *(const float4*)&Vs[t][e0];
    float ka[4] = {kv.x, kv.y, kv.z, kv.w};
    float va[4] = {vv.x, vv.y, vv.z, vv.w};
#pragma unroll
    for (int a = 0; a < 4; ++a)
#pragma unroll
      for (int c = 0; c < 4; ++c)
        acc[a][c] = fmaf(ka[a], va[c], acc[a][c]);
  }
  float* outp = ctx_part + ((size_t)chunk * 64 + n) * 4096;
#pragma unroll
  for (int a = 0; a < 4; ++a)
#pragma unroll
    for (int c = 0; c < 4; ++c)
      outp[(d0 + a) * 64 + e0 + c] = acc[a][c];
}

__global__ __launch_bounds__(256) void reduce_ctx(const float* __restrict__ part,
                                                  float* __restrict__ ctx) {
  const int idx = blockIdx.x * 256 + threadIdx.x;
  float s = 0.f;
#pragma unroll
  for (int c = 0; c < 16; ++c) s += part[(size_t)c * 262144 + idx];
  ctx[idx] = s;
}

// ---------------- content[n,e,t] = sum_d ctx[n,d,e]*q[n,d,t] ----------------
__global__ __launch_bounds__(256) void content_kernel(const float* __restrict__ qkv,
                                                      const float* __restrict__ ctx,
                                                      float* __restrict__ content) {
  const int n = blockIdx.y, chunk = blockIdx.x;
  const int b = n >> 3, h = n & 7;
  __shared__ float cs[4096];
  const float* cp = ctx + (size_t)n * 4096;
  for (int i = threadIdx.x * 4; i < 4096; i += 1024)
    *(float4*)&cs[i] = *(const float4*)&cp[i];
  __syncthreads();
  const int tid = threadIdx.x;
  const int e0 = (tid & 15) * 4;
  const int t0 = chunk * 64 + (tid >> 4) * 4;
  const float* qbase = qkv + (size_t)(h * 64) * 8192 + b * 1024 + t0;
  float acc[4][4] = {{0.f}};
  for (int d = 0; d < 64; ++d) {
    float4 cv = *(const float4*)&cs[d * 64 + e0];
    float4 qv = *(const float4*)(qbase + (size_t)d * 8192);
    float ca[4] = {cv.x, cv.y, cv.z, cv.w};
    float qa[4] = {qv.x, qv.y, qv.z, qv.w};
#pragma unroll
    for (int a = 0; a < 4; ++a)
#pragma unroll
      for (int c = 0; c < 4; ++c)
        acc[a][c] = fmaf(ca[a], qa[c], acc[a][c]);
  }
  float* op = content + ((size_t)n * 64 + e0) * 1024 + t0;
#pragma unroll
  for (int a = 0; a < 4; ++a) {
    float4 rv = {acc[a][0], acc[a][1], acc[a][2], acc[a][3]};
    *(float4*)(op + (size_t)a * 1024) = rv;
  }
}

// ---------------- fused S + BN partial stats, no atomics ----------------
// grid (16, 64): block = (t-chunk of 64, n). part1/part2: [64][1024] per-block partials.
__global__ __launch_bounds__(256) void s_stats(const float* __restrict__ qkv,
                                               const float* __restrict__ PsumT,
                                               float* __restrict__ S,
                                               float* __restrict__ part1,
                                               float* __restrict__ part2) {
  const int tc = blockIdx.x, n = blockIdx.y;
  const int b = n >> 3, h = n & 7;
  const int t0 = tc * 64;
  const int tid = threadIdx.x;
  const int tl = tid & 63, dg = tid >> 6;
  __shared__ float part[4][64];
  __shared__ float s_lds[64];
  const float* qbase = qkv + (size_t)(h * 64) * 8192 + b * 1024 + t0;
  float acc = 0.f;
#pragma unroll
  for (int i = 0; i < 16; ++i) {
    const int d = dg * 16 + i;
    acc = fmaf(qbase[(size_t)d * 8192 + tl], PsumT[d * 1024 + t0 + tl], acc);
  }
  part[dg][tl] = acc;
  __syncthreads();
  if (tid < 64) {
    float s = part[0][tid] + part[1][tid] + part[2][tid] + part[3][tid];
    s_lds[tid] = s;
    S[(size_t)n * 1024 + t0 + tid] = s;
  }
  __syncthreads();
  const float* vbase = qkv + (size_t)(1024 + h * 64) * 8192 + b * 1024 + t0;
  const int blk = n * 16 + tc;
  const float sv = s_lds[tl];
#pragma unroll
  for (int ei = 0; ei < 16; ++ei) {
    const int e = dg * 16 + ei;
    float val = vbase[(size_t)e * 8192 + tl] * sv;
    float a1 = val, a2 = val * val;
#pragma unroll
    for (int off = 32; off; off >>= 1) {
      a1 += __shfl_down(a1, off);
      a2 += __shfl_down(a2, off);
    }
    if (tl == 0) {
      part1[e * 1024 + blk] = a1;
      part2[e * 1024 + blk] = a2;
    }
  }
}

// ---------------- reduce partials -> scale/shift ----------------
__global__ __launch_bounds__(256) void bn_reduce(const float* __restrict__ part1,
                                                 const float* __restrict__ part2,
                                                 const float* __restrict__ gamma,
                                                 const float* __restrict__ beta,
                                                 float* __restrict__ scale,
                                                 float* __restrict__ shift) {
  const int e = blockIdx.x;   // 64
  const int tid = threadIdx.x;
  float a1 = 0.f, a2 = 0.f;
#pragma unroll
  for (int i = 0; i < 4; ++i) {
    a1 += part1[e * 1024 + i * 256 + tid];
    a2 += part2[e * 1024 + i * 256 + tid];
  }
#pragma unroll
  for (int off = 32; off; off >>= 1) {
    a1 += __shfl_down(a1, off);
    a2 += __shfl_down(a2, off);
  }
  __shared__ float r1[4], r2[4];
  const int w = tid >> 6, lane = tid & 63;
  if (lane == 0) { r1[w] = a1; r2[w] = a2; }
  __syncthreads();
  if (tid == 0) {
    float s1 = r1[0] + r1[1] + r1[2] + r1[3];
    float s2 = r2[0] + r2[1] + r2[2] + r2[3];
    const float cnt = 65536.0f;
    float mu = s1 / cnt;
    float var = s2 / cnt - mu * mu;
    float sc = gamma[e] * rsqrtf(var + 1e-5f);
    scale[e] = sc;
    shift[e] = beta[e] - mu * sc;
  }
}

// ---------------- out_build: combined = content + BN(v*S); write transposed bf16 ----------------
__global__ __launch_bounds__(256) void out_build_t(const float* __restrict__ content,
                                                   const float* __restrict__ qkv,
                                                   const float* __restrict__ S,
                                                   const float* __restrict__ scale,
                                                   const float* __restrict__ shift,
                                                   unsigned short* __restrict__ outT) {
  const int n = blockIdx.y, tc = blockIdx.x;   // grid (16, 64)
  const int b = n >> 3, h = n & 7;
  const int t0 = tc * 64;
  __shared__ alignas(16) unsigned short T[64][72];
  const int tid = threadIdx.x;
  const int e = tid >> 2, tq = (tid & 3) * 16;
  const float sc = scale[e], sh = shift[e];
  const float* cp = content + ((size_t)n * 64 + e) * 1024 + t0 + tq;
  const float* vp = qkv + (size_t)(1024 + h * 64 + e) * 8192 + b * 1024 + t0 + tq;
  const float* sp = S + (size_t)n * 1024 + t0 + tq;
#pragma unroll
  for (int i0 = 0; i0 < 16; i0 += 4) {
    float4 c = *(const float4*)(cp + i0);
    float4 v = *(const float4*)(vp + i0);
    float4 s = *(const float4*)(sp + i0);
    T[tq + i0 + 0][e] = f2bf(fmaf(v.x * s.x, sc, c.x + sh));
    T[tq + i0 + 1][e] = f2bf(fmaf(v.y * s.y, sc, c.y + sh));
    T[tq + i0 + 2][e] = f2bf(fmaf(v.z * s.z, sc, c.z + sh));
    T[tq + i0 + 3][e] = f2bf(fmaf(v.w * s.w, sc, c.w + sh));
  }
  __syncthreads();
  const int tl = tid >> 2, dq = (tid & 3) * 16;
  uint4 r0 = *(uint4*)&T[tl][dq];
  uint4 r1 = *(uint4*)&T[tl][dq + 8];
  unsigned short* op = outT + ((size_t)(b * 1024 + t0 + tl)) * 512 + h * 64 + dq;
  *(uint4*)op = r0;
  *(uint4*)(op + 8) = r1;
}

extern "C" void kernel_launch(void* const* d_in, const int* in_sizes, int n_in,
                              void* d_out, int out_size, void* d_ws, size_t ws_size,
                              hipStream_t stream) {
  const float* x       = (const float*)d_in[0];   // (8,1024,512)
  const float* Wqkv    = (const float*)d_in[1];   // (1536,512)
  const float* Wout    = (const float*)d_in[2];   // (512,512)
  const float* bout    = (const float*)d_in[3];   // (512)
  const float* relpos  = (const float*)d_in[4];   // (63,64)
  const float* gamma   = (const float*)d_in[5];   // (64)
  const float* beta    = (const float*)d_in[6];   // (64)
  float* out = (float*)d_out;                     // (8,512,1024)

  float* ws = (float*)d_ws;
  float* qkv      = ws;                       // 1536*8192 = 12,582,912 floats
  float* R        = qkv + 12582912;           // overlay region: 4,194,304 floats
  unsigned short* xb   = (unsigned short*)R;  // xb bf16 [8192][512]  (early life)
  unsigned short* outT = (unsigned short*)R;  // outT bf16 [8192][512] (late life)
  float* ctx_part = R;                        // 16*64*4096 floats    (mid life)
  float* ctx      = R + 4194304;              // 64*4096 = 262,144
  float* content  = ctx + 262144;             // 64*64*1024 = 4,194,304
  float* PsumT    = content + 4194304;        // 65,536
  float* S        = PsumT + 65536;            // 65,536
  float* scale    = S + 65536;                // 64
  float* shift    = scale + 64;               // 64
  float* part1    = shift + 64;               // 64*1024 = 65,536
  float* part2    = part1 + 65536;            // 64*1024 = 65,536

  // 0. PsumT (independent of everything else)
  psum_kernel<<<dim3(4, 64), 256, 0, stream>>>(relpos, PsumT);
  // 1. cast x -> bf16
  cast_x<<<4096, 256, 0, stream>>>(x, xb);
  // 2. qkv = Wqkv @ x^T via bf16 MFMA
  gemm_qkv<<<dim3(64, 12), 256, 0, stream>>>(Wqkv, xb, qkv);
  // 3. S + BN partial stats (reads q,v — independent of softmax)
  s_stats<<<dim3(16, 64), 256, 0, stream>>>(qkv, PsumT, S, part1, part2);
  bn_reduce<<<64, 256, 0, stream>>>(part1, part2, gamma, beta, scale, shift);
  // 4. softmax over t for k rows (in place)
  softmax_k<<<4096, 256, 0, stream>>>(qkv);
  // 5. context partials + reduce (clobbers xb — dead)
  context_kernel<<<dim3(16, 64), 256, 0, stream>>>(qkv, ctx_part);
  reduce_ctx<<<1024, 256, 0, stream>>>(ctx_part, ctx);
  // 6. content_out
  content_kernel<<<dim3(16, 64), 256, 0, stream>>>(qkv, ctx, content);
  // 7. combined out, transposed bf16 (clobbers ctx_part — dead)
  out_build_t<<<dim3(16, 64), 256, 0, stream>>>(content, qkv, S, scale, shift, outT);
  // 8. final GEMM: out = Wout @ comb + bout via bf16 MFMA
  gemm_out<<<dim3(64, 4), 256, 0, stream>>>(Wout, outT, bout, out);
}

// Round 4
// 194.141 us; speedup vs baseline: 2.1628x; 1.1339x over previous
//
#include <hip/hip_runtime.h>
#include <hip/hip_bf16.h>

// Problem constants: B=8, T=1024, DIM=512, H=8, DK=64, L=32, DH=512, DOUT=512
// qkv buffer (bf16) layout: [1536][8192], row o = {q:0..511, k:512..1023, v:1024..1535},
// col = b*1024 + t.  n = b*8 + h; row for (q,h,d) = h*64+d.

typedef short bf16x8 __attribute__((ext_vector_type(8)));
typedef float f32x4 __attribute__((ext_vector_type(4)));

static __device__ __forceinline__ unsigned short f2bf(float f) {
  __hip_bfloat16 h = __float2bfloat16(f);
  return *reinterpret_cast<unsigned short*>(&h);
}
static __device__ __forceinline__ float bf2f(unsigned short u) {
  unsigned int x = ((unsigned int)u) << 16;
  union { unsigned int i; float f; } c; c.i = x;
  return c.f;
}

// ---------------- bf16 MFMA GEMM NT: qkv_bf[1536][8192] = cvt(Wqkv) @ cvt(x)^T ----------------
__global__ __launch_bounds__(256) void gemm_qkv(const float* __restrict__ A,
                                                const float* __restrict__ B,
                                                unsigned short* __restrict__ C) {
  __shared__ alignas(16) unsigned short As[128][40];
  __shared__ alignas(16) unsigned short Bs[128][40];
  const int tid = threadIdx.x;
  const int bm = blockIdx.y * 128, bn = blockIdx.x * 128;
  const int r = tid >> 1;
  const int kc = (tid & 1) * 16;
  const float* Ap = A + (size_t)(bm + r) * 512 + kc;
  const float* Bp = B + (size_t)(bn + r) * 512 + kc;
  const int wave = tid >> 6, lane = tid & 63;
  const int wm = (wave >> 1) * 64, wn = (wave & 1) * 64;
  const int fr = lane & 15, fk = (lane >> 4) * 8;
  f32x4 acc[4][4];
#pragma unroll
  for (int i = 0; i < 4; ++i)
#pragma unroll
    for (int j = 0; j < 4; ++j) acc[i][j] = (f32x4){0.f, 0.f, 0.f, 0.f};
  for (int k0 = 0; k0 < 512; k0 += 32) {
    float4 a0 = *(const float4*)(Ap + k0);
    float4 a1 = *(const float4*)(Ap + k0 + 4);
    float4 a2 = *(const float4*)(Ap + k0 + 8);
    float4 a3 = *(const float4*)(Ap + k0 + 12);
    float4 b0 = *(const float4*)(Bp + k0);
    float4 b1 = *(const float4*)(Bp + k0 + 4);
    float4 b2 = *(const float4*)(Bp + k0 + 8);
    float4 b3 = *(const float4*)(Bp + k0 + 12);
    ushort4 pa0 = {f2bf(a0.x), f2bf(a0.y), f2bf(a0.z), f2bf(a0.w)};
    ushort4 pa1 = {f2bf(a1.x), f2bf(a1.y), f2bf(a1.z), f2bf(a1.w)};
    ushort4 pa2 = {f2bf(a2.x), f2bf(a2.y), f2bf(a2.z), f2bf(a2.w)};
    ushort4 pa3 = {f2bf(a3.x), f2bf(a3.y), f2bf(a3.z), f2bf(a3.w)};
    ushort4 pb0 = {f2bf(b0.x), f2bf(b0.y), f2bf(b0.z), f2bf(b0.w)};
    ushort4 pb1 = {f2bf(b1.x), f2bf(b1.y), f2bf(b1.z), f2bf(b1.w)};
    ushort4 pb2 = {f2bf(b2.x), f2bf(b2.y), f2bf(b2.z), f2bf(b2.w)};
    ushort4 pb3 = {f2bf(b3.x), f2bf(b3.y), f2bf(b3.z), f2bf(b3.w)};
    __syncthreads();
    *(ushort4*)&As[r][kc] = pa0;
    *(ushort4*)&As[r][kc + 4] = pa1;
    *(ushort4*)&As[r][kc + 8] = pa2;
    *(ushort4*)&As[r][kc + 12] = pa3;
    *(ushort4*)&Bs[r][kc] = pb0;
    *(ushort4*)&Bs[r][kc + 4] = pb1;
    *(ushort4*)&Bs[r][kc + 8] = pb2;
    *(ushort4*)&Bs[r][kc + 12] = pb3;
    __syncthreads();
    bf16x8 af[4], bq[4];
#pragma unroll
    for (int mi = 0; mi < 4; ++mi) af[mi] = *(bf16x8*)&As[wm + mi * 16 + fr][fk];
#pragma unroll
    for (int nj = 0; nj < 4; ++nj) bq[nj] = *(bf16x8*)&Bs[wn + nj * 16 + fr][fk];
#pragma unroll
    for (int mi = 0; mi < 4; ++mi)
#pragma unroll
      for (int nj = 0; nj < 4; ++nj)
        acc[mi][nj] = __builtin_amdgcn_mfma_f32_16x16x32_bf16(af[mi], bq[nj], acc[mi][nj], 0, 0, 0);
  }
#pragma unroll
  for (int mi = 0; mi < 4; ++mi) {
    const int row0 = bm + wm + mi * 16 + (lane >> 4) * 4;
#pragma unroll
    for (int nj = 0; nj < 4; ++nj) {
      const int col = bn + wn + nj * 16 + fr;
#pragma unroll
      for (int rr = 0; rr < 4; ++rr)
        C[(size_t)(row0 + rr) * 8192 + col] = f2bf(acc[mi][nj][rr]);
    }
  }
}

// ---------------- bf16 MFMA GEMM NT + bias + remap: out[b][o][t] ----------------
__global__ __launch_bounds__(256) void gemm_out(const float* __restrict__ A,
                                                const unsigned short* __restrict__ B,
                                                const float* __restrict__ bias,
                                                float* __restrict__ out) {
  __shared__ alignas(16) unsigned short As[128][40];
  __shared__ alignas(16) unsigned short Bs[128][40];
  const int tid = threadIdx.x;
  const int bm = blockIdx.y * 128, bn = blockIdx.x * 128;
  const int r = tid >> 1;
  const int kc = (tid & 1) * 16;
  const float* Ap = A + (size_t)(bm + r) * 512 + kc;
  const unsigned short* Bp = B + (size_t)(bn + r) * 512 + kc;
  const int wave = tid >> 6, lane = tid & 63;
  const int wm = (wave >> 1) * 64, wn = (wave & 1) * 64;
  const int fr = lane & 15, fk = (lane >> 4) * 8;
  f32x4 acc[4][4];
#pragma unroll
  for (int i = 0; i < 4; ++i)
#pragma unroll
    for (int j = 0; j < 4; ++j) acc[i][j] = (f32x4){0.f, 0.f, 0.f, 0.f};
  for (int k0 = 0; k0 < 512; k0 += 32) {
    float4 a0 = *(const float4*)(Ap + k0);
    float4 a1 = *(const float4*)(Ap + k0 + 4);
    float4 a2 = *(const float4*)(Ap + k0 + 8);
    float4 a3 = *(const float4*)(Ap + k0 + 12);
    uint4 b0 = *(const uint4*)(Bp + k0);
    uint4 b1 = *(const uint4*)(Bp + k0 + 8);
    ushort4 p0 = {f2bf(a0.x), f2bf(a0.y), f2bf(a0.z), f2bf(a0.w)};
    ushort4 p1 = {f2bf(a1.x), f2bf(a1.y), f2bf(a1.z), f2bf(a1.w)};
    ushort4 p2 = {f2bf(a2.x), f2bf(a2.y), f2bf(a2.z), f2bf(a2.w)};
    ushort4 p3 = {f2bf(a3.x), f2bf(a3.y), f2bf(a3.z), f2bf(a3.w)};
    __syncthreads();
    *(ushort4*)&As[r][kc] = p0;
    *(ushort4*)&As[r][kc + 4] = p1;
    *(ushort4*)&As[r][kc + 8] = p2;
    *(ushort4*)&As[r][kc + 12] = p3;
    *(uint4*)&Bs[r][kc] = b0;
    *(uint4*)&Bs[r][kc + 8] = b1;
    __syncthreads();
    bf16x8 af[4], bq[4];
#pragma unroll
    for (int mi = 0; mi < 4; ++mi) af[mi] = *(bf16x8*)&As[wm + mi * 16 + fr][fk];
#pragma unroll
    for (int nj = 0; nj < 4; ++nj) bq[nj] = *(bf16x8*)&Bs[wn + nj * 16 + fr][fk];
#pragma unroll
    for (int mi = 0; mi < 4; ++mi)
#pragma unroll
      for (int nj = 0; nj < 4; ++nj)
        acc[mi][nj] = __builtin_amdgcn_mfma_f32_16x16x32_bf16(af[mi], bq[nj], acc[mi][nj], 0, 0, 0);
  }
#pragma unroll
  for (int mi = 0; mi < 4; ++mi) {
    const int row0 = bm + wm + mi * 16 + (lane >> 4) * 4;
#pragma unroll
    for (int nj = 0; nj < 4; ++nj) {
      const int col = bn + wn + nj * 16 + fr;   // g = b*1024 + t
      const int b = col >> 10, t = col & 1023;
#pragma unroll
      for (int rr = 0; rr < 4; ++rr)
        out[(size_t)b * 524288 + (size_t)(row0 + rr) * 1024 + t] = acc[mi][nj][rr] + bias[row0 + rr];
    }
  }
}

// ---------------- per-k-row logsumexp: lse[r] = max + log(sum exp(k-max)) ----------------
__global__ __launch_bounds__(256) void kstats(const unsigned short* __restrict__ qkv,
                                              float* __restrict__ lse) {
  const int tid = threadIdx.x;
  const int wave = tid >> 6, lane = tid & 63;
  const int r = blockIdx.x * 4 + wave;     // 0..4095 = hd*8 + b
  const int hd = r >> 3, b = r & 7;
  const unsigned short* row = qkv + (size_t)(512 + hd) * 8192 + b * 1024 + lane * 16;
  uint4 u0 = *(const uint4*)row;
  uint4 u1 = *(const uint4*)(row + 8);
  const unsigned short* us0 = (const unsigned short*)&u0;
  const unsigned short* us1 = (const unsigned short*)&u1;
  float f[16];
#pragma unroll
  for (int i = 0; i < 8; ++i) { f[i] = bf2f(us0[i]); f[8 + i] = bf2f(us1[i]); }
  float m = f[0];
#pragma unroll
  for (int i = 1; i < 16; ++i) m = fmaxf(m, f[i]);
#pragma unroll
  for (int off = 32; off; off >>= 1) m = fmaxf(m, __shfl_xor(m, off));
  float s = 0.f;
#pragma unroll
  for (int i = 0; i < 16; ++i) s += __expf(f[i] - m);
#pragma unroll
  for (int off = 32; off; off >>= 1) s += __shfl_xor(s, off);
  if (lane == 0) lse[r] = m + __logf(s);
}

// ---------------- PsumT[d][t] ----------------
__global__ __launch_bounds__(256) void psum_kernel(const float* __restrict__ relpos,
                                                   float* __restrict__ PsumT) {
  const int d = blockIdx.y;
  const int t = blockIdx.x * 256 + threadIdx.x;
  float acc = 0.f;
  for (int j = 0; j < 63; ++j) {
    int i = t + j - 31;
    float v = relpos[j * 64 + d];
    if (i >= 0 && i < 1024) acc += v;
  }
  PsumT[d * 1024 + t] = acc;
}

// ---------------- context via MFMA with fused softmax-apply ----------------
// grid (4, 64): tc = 256-t chunk, n. ctx_part[tc][n][64][64] fp32 partials.
__global__ __launch_bounds__(256) void context_mfma(const unsigned short* __restrict__ qkv,
                                                    const float* __restrict__ lse,
                                                    float* __restrict__ ctx_part) {
  const int tc = blockIdx.x, n = blockIdx.y;
  const int b = n >> 3, h = n & 7;
  const int tid = threadIdx.x;
  const int wave = tid >> 6, lane = tid & 63;
  __shared__ float ls[64];
  __shared__ float ctx_l[64][68];
  if (tid < 64) ls[tid] = lse[(h * 64 + tid) * 8 + b];
  __syncthreads();
  const int fr = lane & 15, fk = (lane >> 4) * 8;
  const size_t colbase = (size_t)b * 1024 + tc * 256 + wave * 64;
  const unsigned short* kbase = qkv + (size_t)(512 + h * 64) * 8192 + colbase;
  const unsigned short* vbase = qkv + (size_t)(1024 + h * 64) * 8192 + colbase;
  f32x4 acc[4][4];
#pragma unroll
  for (int i = 0; i < 4; ++i)
#pragma unroll
    for (int j = 0; j < 4; ++j) acc[i][j] = (f32x4){0.f, 0.f, 0.f, 0.f};
#pragma unroll
  for (int ks = 0; ks < 2; ++ks) {
    const int tb = ks * 32 + fk;
    bf16x8 aF[4], bF[4];
#pragma unroll
    for (int dt = 0; dt < 4; ++dt) {
      const int row = dt * 16 + fr;
      bf16x8 kv = *(const bf16x8*)(kbase + (size_t)row * 8192 + tb);
      const float lv = ls[row];
      bf16x8 pv;
#pragma unroll
      for (int j = 0; j < 8; ++j)
        pv[j] = (short)f2bf(__expf(bf2f((unsigned short)kv[j]) - lv));
      aF[dt] = pv;
    }
#pragma unroll
    for (int et = 0; et < 4; ++et)
      bF[et] = *(const bf16x8*)(vbase + (size_t)(et * 16 + fr) * 8192 + tb);
#pragma unroll
    for (int dt = 0; dt < 4; ++dt)
#pragma unroll
      for (int et = 0; et < 4; ++et)
        acc[dt][et] = __builtin_amdgcn_mfma_f32_16x16x32_bf16(aF[dt], bF[et], acc[dt][et], 0, 0, 0);
  }
  // cross-wave accumulate in LDS (wave-sequential)
#pragma unroll
  for (int w = 0; w < 4; ++w) {
    if (wave == w) {
#pragma unroll
      for (int dt = 0; dt < 4; ++dt)
#pragma unroll
        for (int et = 0; et < 4; ++et) {
          const int col = et * 16 + fr;
#pragma unroll
          for (int rr = 0; rr < 4; ++rr) {
            const int rw = dt * 16 + (lane >> 4) * 4 + rr;
            if (w == 0) ctx_l[rw][col] = acc[dt][et][rr];
            else ctx_l[rw][col] += acc[dt][et][rr];
          }
        }
    }
    __syncthreads();
  }
  float* outp = ctx_part + ((size_t)tc * 64 + n) * 4096;
  for (int i = tid * 4; i < 4096; i += 1024) {
    const int rw = i >> 6, cc = i & 63;
    *(float4*)(outp + i) = *(const float4*)&ctx_l[rw][cc];
  }
}

// ---------------- reduce 4 ctx partials ----------------
__global__ __launch_bounds__(256) void reduce_ctx(const float* __restrict__ part,
                                                  float* __restrict__ ctx) {
  const int i4 = blockIdx.x * 256 + threadIdx.x;   // 65536 float4s
  const float4* p = (const float4*)part;
  float4 a = p[i4], b = p[65536 + i4], c = p[131072 + i4], d = p[196608 + i4];
  float4 s = {a.x + b.x + c.x + d.x, a.y + b.y + c.y + d.y,
              a.z + b.z + c.z + d.z, a.w + b.w + c.w + d.w};
  ((float4*)ctx)[i4] = s;
}

// ---------------- content[n,e,t] = sum_d ctx[n,d,e]*q[n,d,t] -> bf16 ----------------
__global__ __launch_bounds__(256) void content_kernel(const unsigned short* __restrict__ qkv,
                                                      const float* __restrict__ ctx,
                                                      unsigned short* __restrict__ content) {
  const int n = blockIdx.y, chunk = blockIdx.x;
  const int b = n >> 3, h = n & 7;
  __shared__ float cs[4096];
  const float* cp = ctx + (size_t)n * 4096;
  for (int i = threadIdx.x * 4; i < 4096; i += 1024)
    *(float4*)&cs[i] = *(const float4*)&cp[i];
  __syncthreads();
  const int tid = threadIdx.x;
  const int e0 = (tid & 15) * 4;
  const int t0 = chunk * 64 + (tid >> 4) * 4;
  const unsigned short* qbase = qkv + (size_t)(h * 64) * 8192 + b * 1024 + t0;
  float acc[4][4] = {{0.f}};
  for (int d = 0; d < 64; ++d) {
    float4 cv = *(const float4*)&cs[d * 64 + e0];
    ushort4 qu = *(const ushort4*)(qbase + (size_t)d * 8192);
    float qa[4] = {bf2f(qu.x), bf2f(qu.y), bf2f(qu.z), bf2f(qu.w)};
    float ca[4] = {cv.x, cv.y, cv.z, cv.w};
#pragma unroll
    for (int a = 0; a < 4; ++a)
#pragma unroll
      for (int c = 0; c < 4; ++c)
        acc[a][c] = fmaf(ca[a], qa[c], acc[a][c]);
  }
#pragma unroll
  for (int a = 0; a < 4; ++a) {
    ushort4 rv = {f2bf(acc[a][0]), f2bf(acc[a][1]), f2bf(acc[a][2]), f2bf(acc[a][3])};
    *(ushort4*)(content + ((size_t)n * 64 + e0 + a) * 1024 + t0) = rv;
  }
}

// ---------------- fused S + BN partial stats (bf16 q,v) ----------------
__global__ __launch_bounds__(256) void s_stats(const unsigned short* __restrict__ qkv,
                                               const float* __restrict__ PsumT,
                                               float* __restrict__ S,
                                               float* __restrict__ part1,
                                               float* __restrict__ part2) {
  const int tc = blockIdx.x, n = blockIdx.y;
  const int b = n >> 3, h = n & 7;
  const int t0 = tc * 64;
  const int tid = threadIdx.x;
  const int tl = tid & 63, dg = tid >> 6;
  __shared__ float part[4][64];
  __shared__ float s_lds[64];
  const unsigned short* qbase = qkv + (size_t)(h * 64) * 8192 + b * 1024 + t0;
  float acc = 0.f;
#pragma unroll
  for (int i = 0; i < 16; ++i) {
    const int d = dg * 16 + i;
    acc = fmaf(bf2f(qbase[(size_t)d * 8192 + tl]), PsumT[d * 1024 + t0 + tl], acc);
  }
  part[dg][tl] = acc;
  __syncthreads();
  if (tid < 64) {
    float s = part[0][tid] + part[1][tid] + part[2][tid] + part[3][tid];
    s_lds[tid] = s;
    S[(size_t)n * 1024 + t0 + tid] = s;
  }
  __syncthreads();
  const unsigned short* vbase = qkv + (size_t)(1024 + h * 64) * 8192 + b * 1024 + t0;
  const int blk = n * 16 + tc;
  const float sv = s_lds[tl];
#pragma unroll
  for (int ei = 0; ei < 16; ++ei) {
    const int e = dg * 16 + ei;
    float val = bf2f(vbase[(size_t)e * 8192 + tl]) * sv;
    float a1 = val, a2 = val * val;
#pragma unroll
    for (int off = 32; off; off >>= 1) {
      a1 += __shfl_down(a1, off);
      a2 += __shfl_down(a2, off);
    }
    if (tl == 0) {
      part1[e * 1024 + blk] = a1;
      part2[e * 1024 + blk] = a2;
    }
  }
}

// ---------------- reduce partials -> scale/shift ----------------
__global__ __launch_bounds__(256) void bn_reduce(const float* __restrict__ part1,
                                                 const float* __restrict__ part2,
                                                 const float* __restrict__ gamma,
                                                 const float* __restrict__ beta,
                                                 float* __restrict__ scale,
                                                 float* __restrict__ shift) {
  const int e = blockIdx.x;
  const int tid = threadIdx.x;
  float a1 = 0.f, a2 = 0.f;
#pragma unroll
  for (int i = 0; i < 4; ++i) {
    a1 += part1[e * 1024 + i * 256 + tid];
    a2 += part2[e * 1024 + i * 256 + tid];
  }
#pragma unroll
  for (int off = 32; off; off >>= 1) {
    a1 += __shfl_down(a1, off);
    a2 += __shfl_down(a2, off);
  }
  __shared__ float r1[4], r2[4];
  const int w = tid >> 6, lane = tid & 63;
  if (lane == 0) { r1[w] = a1; r2[w] = a2; }
  __syncthreads();
  if (tid == 0) {
    float s1 = r1[0] + r1[1] + r1[2] + r1[3];
    float s2 = r2[0] + r2[1] + r2[2] + r2[3];
    const float cnt = 65536.0f;
    float mu = s1 / cnt;
    float var = s2 / cnt - mu * mu;
    float sc = gamma[e] * rsqrtf(var + 1e-5f);
    scale[e] = sc;
    shift[e] = beta[e] - mu * sc;
  }
}

// ---------------- out_build: combined = content + BN(v*S); write transposed bf16 ----------------
__global__ __launch_bounds__(256) void out_build_t(const unsigned short* __restrict__ content,
                                                   const unsigned short* __restrict__ qkv,
                                                   const float* __restrict__ S,
                                                   const float* __restrict__ scale,
                                                   const float* __restrict__ shift,
                                                   unsigned short* __restrict__ outT) {
  const int n = blockIdx.y, tc = blockIdx.x;   // grid (16, 64)
  const int b = n >> 3, h = n & 7;
  const int t0 = tc * 64;
  __shared__ alignas(16) unsigned short T[64][72];
  const int tid = threadIdx.x;
  const int e = tid >> 2, tq = (tid & 3) * 16;
  const float sc = scale[e], sh = shift[e];
  const unsigned short* cp = content + ((size_t)n * 64 + e) * 1024 + t0 + tq;
  const unsigned short* vp = qkv + (size_t)(1024 + h * 64 + e) * 8192 + b * 1024 + t0 + tq;
  const float* sp = S + (size_t)n * 1024 + t0 + tq;
  bf16x8 c0 = *(const bf16x8*)cp, c1 = *(const bf16x8*)(cp + 8);
  bf16x8 v0 = *(const bf16x8*)vp, v1 = *(const bf16x8*)(vp + 8);
#pragma unroll
  for (int i = 0; i < 8; ++i) {
    float sf = sp[i];
    T[tq + i][e] = f2bf(fmaf(bf2f((unsigned short)v0[i]) * sf, sc, bf2f((unsigned short)c0[i]) + sh));
    float sf2 = sp[8 + i];
    T[tq + 8 + i][e] = f2bf(fmaf(bf2f((unsigned short)v1[i]) * sf2, sc, bf2f((unsigned short)c1[i]) + sh));
  }
  __syncthreads();
  const int tl = tid >> 2, dq = (tid & 3) * 16;
  uint4 r0 = *(uint4*)&T[tl][dq];
  uint4 r1 = *(uint4*)&T[tl][dq + 8];
  unsigned short* op = outT + ((size_t)(b * 1024 + t0 + tl)) * 512 + h * 64 + dq;
  *(uint4*)op = r0;
  *(uint4*)(op + 8) = r1;
}

extern "C" void kernel_launch(void* const* d_in, const int* in_sizes, int n_in,
                              void* d_out, int out_size, void* d_ws, size_t ws_size,
                              hipStream_t stream) {
  const float* x       = (const float*)d_in[0];   // (8,1024,512)
  const float* Wqkv    = (const float*)d_in[1];   // (1536,512)
  const float* Wout    = (const float*)d_in[2];   // (512,512)
  const float* bout    = (const float*)d_in[3];   // (512)
  const float* relpos  = (const float*)d_in[4];   // (63,64)
  const float* gamma   = (const float*)d_in[5];   // (64)
  const float* beta    = (const float*)d_in[6];   // (64)
  float* out = (float*)d_out;                     // (8,512,1024)

  float* ws = (float*)d_ws;
  unsigned short* qkvb = (unsigned short*)ws;            // 1536*8192 bf16 = 6,291,456 floats
  float* ctx_part = ws + 6291456;                        // 4*64*4096 = 1,048,576
  float* ctx      = ctx_part + 1048576;                  // 64*4096 = 262,144
  float* PsumT    = ctx + 262144;                        // 65,536
  float* S        = PsumT + 65536;                       // 65,536
  float* lse      = S + 65536;                           // 4,096
  float* part1    = lse + 4096;                          // 65,536
  float* part2    = part1 + 65536;                       // 65,536
  float* scale    = part2 + 65536;                       // 64
  float* shift    = scale + 64;                          // 64
  unsigned short* contentb = (unsigned short*)(shift + 64);       // 64*64*1024 bf16
  unsigned short* outT = (unsigned short*)(shift + 64 + 2097152); // 8192*512 bf16

  // 0. PsumT (independent)
  psum_kernel<<<dim3(4, 64), 256, 0, stream>>>(relpos, PsumT);
  // 1. qkv (bf16) = Wqkv @ x^T via bf16 MFMA, fused f32->bf16 on both operands
  gemm_qkv<<<dim3(64, 12), 256, 0, stream>>>(Wqkv, x, qkvb);
  // 2. per-k-row logsumexp
  kstats<<<1024, 256, 0, stream>>>(qkvb, lse);
  // 3. S + BN partial stats
  s_stats<<<dim3(16, 64), 256, 0, stream>>>(qkvb, PsumT, S, part1, part2);
  bn_reduce<<<64, 256, 0, stream>>>(part1, part2, gamma, beta, scale, shift);
  // 4. context via MFMA with fused softmax-apply
  context_mfma<<<dim3(4, 64), 256, 0, stream>>>(qkvb, lse, ctx_part);
  reduce_ctx<<<256, 256, 0, stream>>>(ctx_part, ctx);
  // 5. content_out (bf16 out)
  content_kernel<<<dim3(16, 64), 256, 0, stream>>>(qkvb, ctx, contentb);
  // 6. combined out, transposed bf16
  out_build_t<<<dim3(16, 64), 256, 0, stream>>>(contentb, qkvb, S, scale, shift, outT);
  // 7. final GEMM: out = Wout @ comb + bout via bf16 MFMA
  gemm_out<<<dim3(64, 4), 256, 0, stream>>>(Wout, outT, bout, out);
}

// Round 5
// 165.261 us; speedup vs baseline: 2.5407x; 1.1748x over previous
//
#include <hip/hip_runtime.h>
#include <hip/hip_bf16.h>

// B=8, T=1024, DIM=512, H=8, DK=64, L=32, DH=512, DOUT=512
// qkvb (bf16) layout: [1536][8192], rows {q:0..511,k:512..1023,v:1024..1535}, col = b*1024+t.

typedef short bf16x8 __attribute__((ext_vector_type(8)));
typedef float f32x4 __attribute__((ext_vector_type(4)));

static __device__ __forceinline__ unsigned short f2bf(float f) {
  __hip_bfloat16 h = __float2bfloat16(f);
  return *reinterpret_cast<unsigned short*>(&h);
}
static __device__ __forceinline__ float bf2f(unsigned short u) {
  union { unsigned int i; float f; } c; c.i = ((unsigned int)u) << 16;
  return c.f;
}
static __device__ __forceinline__ void gl_lds16(const unsigned short* g, unsigned short* l) {
  __builtin_amdgcn_global_load_lds((const __attribute__((address_space(1))) unsigned int*)g,
                                   (__attribute__((address_space(3))) unsigned int*)l,
                                   16, 0, 0);
}

// ---------------- fused cast: x, Wqkv, Wout -> bf16 ----------------
__global__ __launch_bounds__(256) void cast_all(const float* __restrict__ x,
                                                const float* __restrict__ wqkv,
                                                const float* __restrict__ wout,
                                                unsigned short* __restrict__ xb,
                                                unsigned short* __restrict__ wqkvb,
                                                unsigned short* __restrict__ woutb) {
  int j = blockIdx.x * 256 + threadIdx.x;   // float4 index; totals: 1048576 + 196608 + 65536
  const float* src; unsigned short* dst;
  if (j < 1048576) { src = x; dst = xb; }
  else if (j < 1245184) { j -= 1048576; src = wqkv; dst = wqkvb; }
  else { j -= 1245184; src = wout; dst = woutb; }
  float4 v = ((const float4*)src)[j];
  ushort4 o = {f2bf(v.x), f2bf(v.y), f2bf(v.z), f2bf(v.w)};
  ((ushort4*)dst)[j] = o;
}

// ---------------- m97-style bf16 MFMA GEMM NT core (128x128 tile, BK=32) ----------------
// A[M][512], B[N][512] bf16; swizzled LDS via per-lane source-address permutation.
// chunk(row,c) stored at LDS chunk row*4 + (c ^ ((row>>1)&3)); chunk = 16B = 8 bf16.

__global__ __launch_bounds__(256) void gemm_qkv(const unsigned short* __restrict__ A,
                                                const unsigned short* __restrict__ B,
                                                unsigned short* __restrict__ C) {
  __shared__ alignas(16) unsigned short As[4096];
  __shared__ alignas(16) unsigned short Bs[4096];
  const int tid = threadIdx.x;
  const int wave = tid >> 6, lane = tid & 63;
  const int bm = blockIdx.y * 128, bn = blockIdx.x * 128;
  const int wm = (wave >> 1) * 64, wn = (wave & 1) * 64;
  const int fr = lane & 15, cq = lane >> 4;
  const int ch0 = tid, ch1 = 256 + tid;
  const int r0 = ch0 >> 2, c0 = (ch0 & 3) ^ ((r0 >> 1) & 3);
  const int r1 = ch1 >> 2, c1 = (ch1 & 3) ^ ((r1 >> 1) & 3);
  unsigned short* la0 = As + (wave * 64) * 8;
  unsigned short* la1 = As + (256 + wave * 64) * 8;
  unsigned short* lb0 = Bs + (wave * 64) * 8;
  unsigned short* lb1 = Bs + (256 + wave * 64) * 8;
  const unsigned short* Ar0 = A + (size_t)(bm + r0) * 512 + c0 * 8;
  const unsigned short* Ar1 = A + (size_t)(bm + r1) * 512 + c1 * 8;
  const unsigned short* Br0 = B + (size_t)(bn + r0) * 512 + c0 * 8;
  const unsigned short* Br1 = B + (size_t)(bn + r1) * 512 + c1 * 8;
  int offA[4], offB[4];
#pragma unroll
  for (int i = 0; i < 4; ++i) {
    int ra = wm + i * 16 + fr;
    offA[i] = (ra * 4 + (cq ^ ((ra >> 1) & 3))) * 8;
    int rb = wn + i * 16 + fr;
    offB[i] = (rb * 4 + (cq ^ ((rb >> 1) & 3))) * 8;
  }
  f32x4 acc[4][4];
#pragma unroll
  for (int i = 0; i < 4; ++i)
#pragma unroll
    for (int j = 0; j < 4; ++j) acc[i][j] = (f32x4){0.f, 0.f, 0.f, 0.f};
  for (int k0 = 0; k0 < 512; k0 += 32) {
    __syncthreads();
    gl_lds16(Ar0 + k0, la0);
    gl_lds16(Ar1 + k0, la1);
    gl_lds16(Br0 + k0, lb0);
    gl_lds16(Br1 + k0, lb1);
    __builtin_amdgcn_s_waitcnt(0);
    __syncthreads();
    bf16x8 af[4], bq[4];
#pragma unroll
    for (int mi = 0; mi < 4; ++mi) af[mi] = *(const bf16x8*)(As + offA[mi]);
#pragma unroll
    for (int nj = 0; nj < 4; ++nj) bq[nj] = *(const bf16x8*)(Bs + offB[nj]);
#pragma unroll
    for (int mi = 0; mi < 4; ++mi)
#pragma unroll
      for (int nj = 0; nj < 4; ++nj)
        acc[mi][nj] = __builtin_amdgcn_mfma_f32_16x16x32_bf16(af[mi], bq[nj], acc[mi][nj], 0, 0, 0);
  }
#pragma unroll
  for (int mi = 0; mi < 4; ++mi) {
    const int row0 = bm + wm + mi * 16 + (lane >> 4) * 4;
#pragma unroll
    for (int nj = 0; nj < 4; ++nj) {
      const int col = bn + wn + nj * 16 + fr;
#pragma unroll
      for (int rr = 0; rr < 4; ++rr)
        C[(size_t)(row0 + rr) * 8192 + col] = f2bf(acc[mi][nj][rr]);
    }
  }
}

__global__ __launch_bounds__(256) void gemm_out(const unsigned short* __restrict__ A,
                                                const unsigned short* __restrict__ B,
                                                const float* __restrict__ bias,
                                                float* __restrict__ out) {
  __shared__ alignas(16) unsigned short As[4096];
  __shared__ alignas(16) unsigned short Bs[4096];
  const int tid = threadIdx.x;
  const int wave = tid >> 6, lane = tid & 63;
  const int bm = blockIdx.y * 128, bn = blockIdx.x * 128;
  const int wm = (wave >> 1) * 64, wn = (wave & 1) * 64;
  const int fr = lane & 15, cq = lane >> 4;
  const int ch0 = tid, ch1 = 256 + tid;
  const int r0 = ch0 >> 2, c0 = (ch0 & 3) ^ ((r0 >> 1) & 3);
  const int r1 = ch1 >> 2, c1 = (ch1 & 3) ^ ((r1 >> 1) & 3);
  unsigned short* la0 = As + (wave * 64) * 8;
  unsigned short* la1 = As + (256 + wave * 64) * 8;
  unsigned short* lb0 = Bs + (wave * 64) * 8;
  unsigned short* lb1 = Bs + (256 + wave * 64) * 8;
  const unsigned short* Ar0 = A + (size_t)(bm + r0) * 512 + c0 * 8;
  const unsigned short* Ar1 = A + (size_t)(bm + r1) * 512 + c1 * 8;
  const unsigned short* Br0 = B + (size_t)(bn + r0) * 512 + c0 * 8;
  const unsigned short* Br1 = B + (size_t)(bn + r1) * 512 + c1 * 8;
  int offA[4], offB[4];
#pragma unroll
  for (int i = 0; i < 4; ++i) {
    int ra = wm + i * 16 + fr;
    offA[i] = (ra * 4 + (cq ^ ((ra >> 1) & 3))) * 8;
    int rb = wn + i * 16 + fr;
    offB[i] = (rb * 4 + (cq ^ ((rb >> 1) & 3))) * 8;
  }
  f32x4 acc[4][4];
#pragma unroll
  for (int i = 0; i < 4; ++i)
#pragma unroll
    for (int j = 0; j < 4; ++j) acc[i][j] = (f32x4){0.f, 0.f, 0.f, 0.f};
  for (int k0 = 0; k0 < 512; k0 += 32) {
    __syncthreads();
    gl_lds16(Ar0 + k0, la0);
    gl_lds16(Ar1 + k0, la1);
    gl_lds16(Br0 + k0, lb0);
    gl_lds16(Br1 + k0, lb1);
    __builtin_amdgcn_s_waitcnt(0);
    __syncthreads();
    bf16x8 af[4], bq[4];
#pragma unroll
    for (int mi = 0; mi < 4; ++mi) af[mi] = *(const bf16x8*)(As + offA[mi]);
#pragma unroll
    for (int nj = 0; nj < 4; ++nj) bq[nj] = *(const bf16x8*)(Bs + offB[nj]);
#pragma unroll
    for (int mi = 0; mi < 4; ++mi)
#pragma unroll
      for (int nj = 0; nj < 4; ++nj)
        acc[mi][nj] = __builtin_amdgcn_mfma_f32_16x16x32_bf16(af[mi], bq[nj], acc[mi][nj], 0, 0, 0);
  }
#pragma unroll
  for (int mi = 0; mi < 4; ++mi) {
    const int row0 = bm + wm + mi * 16 + (lane >> 4) * 4;
#pragma unroll
    for (int nj = 0; nj < 4; ++nj) {
      const int col = bn + wn + nj * 16 + fr;   // g = b*1024 + t
      const int b = col >> 10, t = col & 1023;
#pragma unroll
      for (int rr = 0; rr < 4; ++rr)
        out[(size_t)b * 524288 + (size_t)(row0 + rr) * 1024 + t] = acc[mi][nj][rr] + bias[row0 + rr];
    }
  }
}

// ---------------- per-k-row logsumexp ----------------
__global__ __launch_bounds__(256) void kstats(const unsigned short* __restrict__ qkv,
                                              float* __restrict__ lse) {
  const int tid = threadIdx.x;
  const int wave = tid >> 6, lane = tid & 63;
  const int r = blockIdx.x * 4 + wave;     // 0..4095 = hd*8 + b
  const int hd = r >> 3, b = r & 7;
  const unsigned short* row = qkv + (size_t)(512 + hd) * 8192 + b * 1024 + lane * 16;
  uint4 u0 = *(const uint4*)row;
  uint4 u1 = *(const uint4*)(row + 8);
  const unsigned short* us0 = (const unsigned short*)&u0;
  const unsigned short* us1 = (const unsigned short*)&u1;
  float f[16];
#pragma unroll
  for (int i = 0; i < 8; ++i) { f[i] = bf2f(us0[i]); f[8 + i] = bf2f(us1[i]); }
  float m = f[0];
#pragma unroll
  for (int i = 1; i < 16; ++i) m = fmaxf(m, f[i]);
#pragma unroll
  for (int off = 32; off; off >>= 1) m = fmaxf(m, __shfl_xor(m, off));
  float s = 0.f;
#pragma unroll
  for (int i = 0; i < 16; ++i) s += __expf(f[i] - m);
#pragma unroll
  for (int off = 32; off; off >>= 1) s += __shfl_xor(s, off);
  if (lane == 0) lse[r] = m + __logf(s);
}

// ---------------- PsumT[d][t] ----------------
__global__ __launch_bounds__(256) void psum_kernel(const float* __restrict__ relpos,
                                                   float* __restrict__ PsumT) {
  const int d = blockIdx.y;
  const int t = blockIdx.x * 256 + threadIdx.x;
  float acc = 0.f;
  for (int j = 0; j < 63; ++j) {
    int i = t + j - 31;
    float v = relpos[j * 64 + d];
    if (i >= 0 && i < 1024) acc += v;
  }
  PsumT[d * 1024 + t] = acc;
}

// ---------------- context via MFMA with fused softmax-apply ----------------
__global__ __launch_bounds__(256) void context_mfma(const unsigned short* __restrict__ qkv,
                                                    const float* __restrict__ lse,
                                                    float* __restrict__ ctx_part) {
  const int tc = blockIdx.x, n = blockIdx.y;
  const int b = n >> 3, h = n & 7;
  const int tid = threadIdx.x;
  const int wave = tid >> 6, lane = tid & 63;
  __shared__ float ls[64];
  __shared__ float ctx_l[64][68];
  if (tid < 64) ls[tid] = lse[(h * 64 + tid) * 8 + b];
  __syncthreads();
  const int fr = lane & 15, fk = (lane >> 4) * 8;
  const size_t colbase = (size_t)b * 1024 + tc * 256 + wave * 64;
  const unsigned short* kbase = qkv + (size_t)(512 + h * 64) * 8192 + colbase;
  const unsigned short* vbase = qkv + (size_t)(1024 + h * 64) * 8192 + colbase;
  f32x4 acc[4][4];
#pragma unroll
  for (int i = 0; i < 4; ++i)
#pragma unroll
    for (int j = 0; j < 4; ++j) acc[i][j] = (f32x4){0.f, 0.f, 0.f, 0.f};
#pragma unroll
  for (int ks = 0; ks < 2; ++ks) {
    const int tb = ks * 32 + fk;
    bf16x8 aF[4], bF[4];
#pragma unroll
    for (int dt = 0; dt < 4; ++dt) {
      const int row = dt * 16 + fr;
      bf16x8 kv = *(const bf16x8*)(kbase + (size_t)row * 8192 + tb);
      const float lv = ls[row];
      bf16x8 pv;
#pragma unroll
      for (int j = 0; j < 8; ++j)
        pv[j] = (short)f2bf(__expf(bf2f((unsigned short)kv[j]) - lv));
      aF[dt] = pv;
    }
#pragma unroll
    for (int et = 0; et < 4; ++et)
      bF[et] = *(const bf16x8*)(vbase + (size_t)(et * 16 + fr) * 8192 + tb);
#pragma unroll
    for (int dt = 0; dt < 4; ++dt)
#pragma unroll
      for (int et = 0; et < 4; ++et)
        acc[dt][et] = __builtin_amdgcn_mfma_f32_16x16x32_bf16(aF[dt], bF[et], acc[dt][et], 0, 0, 0);
  }
#pragma unroll
  for (int w = 0; w < 4; ++w) {
    if (wave == w) {
#pragma unroll
      for (int dt = 0; dt < 4; ++dt)
#pragma unroll
        for (int et = 0; et < 4; ++et) {
          const int col = et * 16 + fr;
#pragma unroll
          for (int rr = 0; rr < 4; ++rr) {
            const int rw = dt * 16 + (lane >> 4) * 4 + rr;
            if (w == 0) ctx_l[rw][col] = acc[dt][et][rr];
            else ctx_l[rw][col] += acc[dt][et][rr];
          }
        }
    }
    __syncthreads();
  }
  float* outp = ctx_part + ((size_t)tc * 64 + n) * 4096;
  for (int i = tid * 4; i < 4096; i += 1024) {
    const int rw = i >> 6, cc = i & 63;
    *(float4*)(outp + i) = *(const float4*)&ctx_l[rw][cc];
  }
}

__global__ __launch_bounds__(256) void reduce_ctx(const float* __restrict__ part,
                                                  float* __restrict__ ctx) {
  const int i4 = blockIdx.x * 256 + threadIdx.x;
  const float4* p = (const float4*)part;
  float4 a = p[i4], b = p[65536 + i4], c = p[131072 + i4], d = p[196608 + i4];
  float4 s = {a.x + b.x + c.x + d.x, a.y + b.y + c.y + d.y,
              a.z + b.z + c.z + d.z, a.w + b.w + c.w + d.w};
  ((float4*)ctx)[i4] = s;
}

// ---------------- fused S + BN partial stats (vectorized) ----------------
__global__ __launch_bounds__(256) void s_stats(const unsigned short* __restrict__ qkv,
                                               const float* __restrict__ PsumT,
                                               float* __restrict__ S,
                                               float* __restrict__ part1,
                                               float* __restrict__ part2) {
  const int tc = blockIdx.x, n = blockIdx.y;   // grid (16,64)
  const int b = n >> 3, h = n & 7;
  const int t0 = tc * 64;
  const int tid = threadIdx.x, wave = tid >> 6, lane = tid & 63;
  const int tg = lane & 7, rg = lane >> 3;
  __shared__ float swave[4][64];
  __shared__ float s_lds[64];
  const unsigned short* qbase = qkv + (size_t)(h * 64) * 8192 + b * 1024 + t0 + tg * 8;
  const float* pbase = PsumT + t0 + tg * 8;
  float acc[8] = {0.f};
#pragma unroll
  for (int i = 0; i < 2; ++i) {
    const int d = wave * 16 + i * 8 + rg;
    bf16x8 qv = *(const bf16x8*)(qbase + (size_t)d * 8192);
    float4 p0 = *(const float4*)(pbase + d * 1024);
    float4 p1 = *(const float4*)(pbase + d * 1024 + 4);
    float p[8] = {p0.x, p0.y, p0.z, p0.w, p1.x, p1.y, p1.z, p1.w};
#pragma unroll
    for (int j = 0; j < 8; ++j) acc[j] = fmaf(bf2f((unsigned short)qv[j]), p[j], acc[j]);
  }
#pragma unroll
  for (int off = 8; off < 64; off <<= 1)
#pragma unroll
    for (int j = 0; j < 8; ++j) acc[j] += __shfl_xor(acc[j], off);
  if (rg == 0) {
#pragma unroll
    for (int j = 0; j < 8; ++j) swave[wave][tg * 8 + j] = acc[j];
  }
  __syncthreads();
  if (tid < 64) {
    float s = swave[0][tid] + swave[1][tid] + swave[2][tid] + swave[3][tid];
    s_lds[tid] = s;
    S[(size_t)n * 1024 + t0 + tid] = s;
  }
  __syncthreads();
  const unsigned short* vbase = qkv + (size_t)(1024 + h * 64) * 8192 + b * 1024 + t0 + tg * 8;
  const int blk = n * 16 + tc;
  float sv[8];
#pragma unroll
  for (int j = 0; j < 8; ++j) sv[j] = s_lds[tg * 8 + j];
#pragma unroll
  for (int i = 0; i < 2; ++i) {
    const int e = wave * 16 + i * 8 + rg;
    bf16x8 vv = *(const bf16x8*)(vbase + (size_t)e * 8192);
    float a1 = 0.f, a2 = 0.f;
#pragma unroll
    for (int j = 0; j < 8; ++j) {
      float val = bf2f((unsigned short)vv[j]) * sv[j];
      a1 += val;
      a2 = fmaf(val, val, a2);
    }
#pragma unroll
    for (int off = 1; off < 8; off <<= 1) {
      a1 += __shfl_xor(a1, off);
      a2 += __shfl_xor(a2, off);
    }
    if (tg == 0) {
      part1[e * 1024 + blk] = a1;
      part2[e * 1024 + blk] = a2;
    }
  }
}

__global__ __launch_bounds__(256) void bn_reduce(const float* __restrict__ part1,
                                                 const float* __restrict__ part2,
                                                 const float* __restrict__ gamma,
                                                 const float* __restrict__ beta,
                                                 float* __restrict__ scale,
                                                 float* __restrict__ shift) {
  const int e = blockIdx.x;
  const int tid = threadIdx.x;
  float a1 = 0.f, a2 = 0.f;
#pragma unroll
  for (int i = 0; i < 4; ++i) {
    a1 += part1[e * 1024 + i * 256 + tid];
    a2 += part2[e * 1024 + i * 256 + tid];
  }
#pragma unroll
  for (int off = 32; off; off >>= 1) {
    a1 += __shfl_down(a1, off);
    a2 += __shfl_down(a2, off);
  }
  __shared__ float r1[4], r2[4];
  const int w = tid >> 6, lane = tid & 63;
  if (lane == 0) { r1[w] = a1; r2[w] = a2; }
  __syncthreads();
  if (tid == 0) {
    float s1 = r1[0] + r1[1] + r1[2] + r1[3];
    float s2 = r2[0] + r2[1] + r2[2] + r2[3];
    const float cnt = 65536.0f;
    float mu = s1 / cnt;
    float var = s2 / cnt - mu * mu;
    float sc = gamma[e] * rsqrtf(var + 1e-5f);
    scale[e] = sc;
    shift[e] = beta[e] - mu * sc;
  }
}

// ---------------- fused content + BN-combine + transpose -> outT bf16 ----------------
__global__ __launch_bounds__(256) void content_out_t(const unsigned short* __restrict__ qkv,
                                                     const float* __restrict__ ctx,
                                                     const float* __restrict__ S,
                                                     const float* __restrict__ scale,
                                                     const float* __restrict__ shift,
                                                     unsigned short* __restrict__ outT) {
  const int chunk = blockIdx.x, n = blockIdx.y;   // grid (16, 64)
  const int b = n >> 3, h = n & 7;
  const int t0 = chunk * 64;
  __shared__ float cs[4096];
  __shared__ alignas(16) unsigned short T[64][72];
  const float* cp = ctx + (size_t)n * 4096;
  for (int i = threadIdx.x * 4; i < 4096; i += 1024)
    *(float4*)&cs[i] = *(const float4*)&cp[i];
  __syncthreads();
  const int tid = threadIdx.x;
  const int e0 = (tid & 15) * 4;
  const int tq = (tid >> 4) * 4;
  const unsigned short* qbase = qkv + (size_t)(h * 64) * 8192 + b * 1024 + t0 + tq;
  float acc[4][4] = {{0.f}};
  for (int d = 0; d < 64; ++d) {
    float4 cv = *(const float4*)&cs[d * 64 + e0];
    ushort4 qu = *(const ushort4*)(qbase + (size_t)d * 8192);
    float qa[4] = {bf2f(qu.x), bf2f(qu.y), bf2f(qu.z), bf2f(qu.w)};
    float ca[4] = {cv.x, cv.y, cv.z, cv.w};
#pragma unroll
    for (int a = 0; a < 4; ++a)
#pragma unroll
      for (int c = 0; c < 4; ++c)
        acc[a][c] = fmaf(ca[a], qa[c], acc[a][c]);
  }
  float4 svv = *(const float4*)(S + (size_t)n * 1024 + t0 + tq);
  float sa[4] = {svv.x, svv.y, svv.z, svv.w};
  float4 scv = *(const float4*)(scale + e0);
  float4 shv = *(const float4*)(shift + e0);
  float sc[4] = {scv.x, scv.y, scv.z, scv.w};
  float sh[4] = {shv.x, shv.y, shv.z, shv.w};
#pragma unroll
  for (int a = 0; a < 4; ++a) {
    ushort4 vu = *(const ushort4*)(qkv + (size_t)(1024 + h * 64 + e0 + a) * 8192 + b * 1024 + t0 + tq);
    float va[4] = {bf2f(vu.x), bf2f(vu.y), bf2f(vu.z), bf2f(vu.w)};
#pragma unroll
    for (int c = 0; c < 4; ++c)
      T[tq + c][e0 + a] = f2bf(fmaf(va[c] * sa[c], sc[a], acc[a][c] + sh[a]));
  }
  __syncthreads();
  const int tl = tid >> 2, dq = (tid & 3) * 16;
  uint4 r0 = *(uint4*)&T[tl][dq];
  uint4 r1 = *(uint4*)&T[tl][dq + 8];
  unsigned short* op = outT + ((size_t)(b * 1024 + t0 + tl)) * 512 + h * 64 + dq;
  *(uint4*)op = r0;
  *(uint4*)(op + 8) = r1;
}

extern "C" void kernel_launch(void* const* d_in, const int* in_sizes, int n_in,
                              void* d_out, int out_size, void* d_ws, size_t ws_size,
                              hipStream_t stream) {
  const float* x       = (const float*)d_in[0];
  const float* Wqkv    = (const float*)d_in[1];
  const float* Wout    = (const float*)d_in[2];
  const float* bout    = (const float*)d_in[3];
  const float* relpos  = (const float*)d_in[4];
  const float* gamma   = (const float*)d_in[5];
  const float* beta    = (const float*)d_in[6];
  float* out = (float*)d_out;

  float* ws = (float*)d_ws;
  unsigned short* qkvb  = (unsigned short*)ws;             // 12,582,912 shorts (6,291,456 f)
  float* p = ws + 6291456;
  unsigned short* xb    = (unsigned short*)p;  p += 2097152;   // 8192x512 bf16
  unsigned short* wqkvb = (unsigned short*)p;  p += 393216;    // 1536x512 bf16
  unsigned short* woutb = (unsigned short*)p;  p += 131072;    // 512x512 bf16
  float* ctx_part = p;  p += 1048576;                          // 4*64*4096
  float* ctx      = p;  p += 262144;
  float* PsumT    = p;  p += 65536;
  float* S        = p;  p += 65536;
  float* lse      = p;  p += 4096;
  float* part1    = p;  p += 65536;
  float* part2    = p;  p += 65536;
  float* scale    = p;  p += 64;
  float* shift    = p;  p += 64;
  unsigned short* outT = (unsigned short*)p;                   // 8192x512 bf16

  // 0. cast inputs to bf16 (x, Wqkv, Wout)
  cast_all<<<5120, 256, 0, stream>>>(x, Wqkv, Wout, xb, wqkvb, woutb);
  // 1. PsumT
  psum_kernel<<<dim3(4, 64), 256, 0, stream>>>(relpos, PsumT);
  // 2. qkv (bf16) = Wqkv @ x^T, m97-style global_load_lds GEMM
  gemm_qkv<<<dim3(64, 12), 256, 0, stream>>>(wqkvb, xb, qkvb);
  // 3. per-k-row logsumexp
  kstats<<<1024, 256, 0, stream>>>(qkvb, lse);
  // 4. S + BN partial stats
  s_stats<<<dim3(16, 64), 256, 0, stream>>>(qkvb, PsumT, S, part1, part2);
  bn_reduce<<<64, 256, 0, stream>>>(part1, part2, gamma, beta, scale, shift);
  // 5. context via MFMA with fused softmax-apply
  context_mfma<<<dim3(4, 64), 256, 0, stream>>>(qkvb, lse, ctx_part);
  reduce_ctx<<<256, 256, 0, stream>>>(ctx_part, ctx);
  // 6. fused content + BN-combine + transpose
  content_out_t<<<dim3(16, 64), 256, 0, stream>>>(qkvb, ctx, S, scale, shift, outT);
  // 7. final GEMM: out = Wout @ comb + bout
  gemm_out<<<dim3(64, 4), 256, 0, stream>>>(woutb, outT, bout, out);
}

// Round 6
// 163.339 us; speedup vs baseline: 2.5706x; 1.0118x over previous
//
#include <hip/hip_runtime.h>
#include <hip/hip_bf16.h>

// B=8, T=1024, DIM=512, H=8, DK=64, L=32, DH=512, DOUT=512
// qkvb (bf16) layout: [1536][8192], rows {q:0..511,k:512..1023,v:1024..1535}, col = b*1024+t.

typedef short bf16x8 __attribute__((ext_vector_type(8)));
typedef float f32x4 __attribute__((ext_vector_type(4)));

static __device__ __forceinline__ unsigned short f2bf(float f) {
  __hip_bfloat16 h = __float2bfloat16(f);
  return *reinterpret_cast<unsigned short*>(&h);
}
static __device__ __forceinline__ float bf2f(unsigned short u) {
  union { unsigned int i; float f; } c; c.i = ((unsigned int)u) << 16;
  return c.f;
}
static __device__ __forceinline__ void gl_lds16(const unsigned short* g, unsigned short* l) {
  __builtin_amdgcn_global_load_lds((const __attribute__((address_space(1))) unsigned int*)g,
                                   (__attribute__((address_space(3))) unsigned int*)l,
                                   16, 0, 0);
}

// ---------------- prep: cast x/Wqkv/Wout -> bf16  +  PsumT ----------------
__global__ __launch_bounds__(256) void prep(const float* __restrict__ x,
                                            const float* __restrict__ wqkv,
                                            const float* __restrict__ wout,
                                            const float* __restrict__ relpos,
                                            unsigned short* __restrict__ xb,
                                            unsigned short* __restrict__ wqkvb,
                                            unsigned short* __restrict__ woutb,
                                            float* __restrict__ PsumT) {
  const int bx = blockIdx.x;
  if (bx < 5120) {
    int j = bx * 256 + threadIdx.x;   // float4 idx: x 1048576 | wqkv 196608 | wout 65536
    const float* src; unsigned short* dst;
    if (j < 1048576) { src = x; dst = xb; }
    else if (j < 1245184) { j -= 1048576; src = wqkv; dst = wqkvb; }
    else { j -= 1245184; src = wout; dst = woutb; }
    float4 v = ((const float4*)src)[j];
    ushort4 o = {f2bf(v.x), f2bf(v.y), f2bf(v.z), f2bf(v.w)};
    ((ushort4*)dst)[j] = o;
  } else {
    const int idx = bx - 5120;            // 256 blocks: d = idx>>2, t-chunk = idx&3
    const int d = idx >> 2;
    const int t = (idx & 3) * 256 + threadIdx.x;
    float acc = 0.f;
    for (int j = 0; j < 63; ++j) {
      int i = t + j - 31;
      float v = relpos[j * 64 + d];
      if (i >= 0 && i < 1024) acc += v;
    }
    PsumT[d * 1024 + t] = acc;
  }
}

// ---------------- BK=64 m97-style bf16 MFMA GEMM NT (128x128 tile) ----------------
// LDS: 128 rows x 8 chunks of 16B; chunk c of row stored at position c ^ (row&7).

__global__ __launch_bounds__(256) void gemm_qkv(const unsigned short* __restrict__ A,
                                                const unsigned short* __restrict__ B,
                                                unsigned short* __restrict__ C) {
  __shared__ alignas(16) unsigned short As[8192];
  __shared__ alignas(16) unsigned short Bs[8192];
  const int tid = threadIdx.x;
  const int wave = tid >> 6, lane = tid & 63;
  const int bm = blockIdx.y * 128, bn = blockIdx.x * 128;
  const int wm = (wave >> 1) * 64, wn = (wave & 1) * 64;
  const int fr = lane & 15, cq = lane >> 4;
  const unsigned short* srcA[4];
  const unsigned short* srcB[4];
#pragma unroll
  for (int j = 0; j < 4; ++j) {
    const int s = tid + j * 256;
    const int row = s >> 3, cp = s & 7;
    const int c = cp ^ (row & 7);
    srcA[j] = A + (size_t)(bm + row) * 512 + c * 8;
    srcB[j] = B + (size_t)(bn + row) * 512 + c * 8;
  }
  int offA[4][2], offB[4][2];
#pragma unroll
  for (int i = 0; i < 4; ++i)
#pragma unroll
    for (int ks = 0; ks < 2; ++ks) {
      int ra = wm + i * 16 + fr;
      offA[i][ks] = (ra * 8 + ((ks * 4 + cq) ^ (ra & 7))) * 8;
      int rb = wn + i * 16 + fr;
      offB[i][ks] = (rb * 8 + ((ks * 4 + cq) ^ (rb & 7))) * 8;
    }
  f32x4 acc[4][4];
#pragma unroll
  for (int i = 0; i < 4; ++i)
#pragma unroll
    for (int j = 0; j < 4; ++j) acc[i][j] = (f32x4){0.f, 0.f, 0.f, 0.f};
  for (int k0 = 0; k0 < 512; k0 += 64) {
    __syncthreads();
#pragma unroll
    for (int j = 0; j < 4; ++j) {
      gl_lds16(srcA[j] + k0, As + (wave * 64 + j * 256) * 8);
      gl_lds16(srcB[j] + k0, Bs + (wave * 64 + j * 256) * 8);
    }
    __builtin_amdgcn_s_waitcnt(0);
    __syncthreads();
#pragma unroll
    for (int ks = 0; ks < 2; ++ks) {
      bf16x8 af[4], bq[4];
#pragma unroll
      for (int mi = 0; mi < 4; ++mi) af[mi] = *(const bf16x8*)(As + offA[mi][ks]);
#pragma unroll
      for (int nj = 0; nj < 4; ++nj) bq[nj] = *(const bf16x8*)(Bs + offB[nj][ks]);
#pragma unroll
      for (int mi = 0; mi < 4; ++mi)
#pragma unroll
        for (int nj = 0; nj < 4; ++nj)
          acc[mi][nj] = __builtin_amdgcn_mfma_f32_16x16x32_bf16(af[mi], bq[nj], acc[mi][nj], 0, 0, 0);
    }
  }
#pragma unroll
  for (int mi = 0; mi < 4; ++mi) {
    const int row0 = bm + wm + mi * 16 + (lane >> 4) * 4;
#pragma unroll
    for (int nj = 0; nj < 4; ++nj) {
      const int col = bn + wn + nj * 16 + fr;
#pragma unroll
      for (int rr = 0; rr < 4; ++rr)
        C[(size_t)(row0 + rr) * 8192 + col] = f2bf(acc[mi][nj][rr]);
    }
  }
}

__global__ __launch_bounds__(256) void gemm_out(const unsigned short* __restrict__ A,
                                                const unsigned short* __restrict__ B,
                                                const float* __restrict__ bias,
                                                float* __restrict__ out) {
  __shared__ alignas(16) unsigned short As[8192];
  __shared__ alignas(16) unsigned short Bs[8192];
  const int tid = threadIdx.x;
  const int wave = tid >> 6, lane = tid & 63;
  const int bm = blockIdx.y * 128, bn = blockIdx.x * 128;
  const int wm = (wave >> 1) * 64, wn = (wave & 1) * 64;
  const int fr = lane & 15, cq = lane >> 4;
  const unsigned short* srcA[4];
  const unsigned short* srcB[4];
#pragma unroll
  for (int j = 0; j < 4; ++j) {
    const int s = tid + j * 256;
    const int row = s >> 3, cp = s & 7;
    const int c = cp ^ (row & 7);
    srcA[j] = A + (size_t)(bm + row) * 512 + c * 8;
    srcB[j] = B + (size_t)(bn + row) * 512 + c * 8;
  }
  int offA[4][2], offB[4][2];
#pragma unroll
  for (int i = 0; i < 4; ++i)
#pragma unroll
    for (int ks = 0; ks < 2; ++ks) {
      int ra = wm + i * 16 + fr;
      offA[i][ks] = (ra * 8 + ((ks * 4 + cq) ^ (ra & 7))) * 8;
      int rb = wn + i * 16 + fr;
      offB[i][ks] = (rb * 8 + ((ks * 4 + cq) ^ (rb & 7))) * 8;
    }
  f32x4 acc[4][4];
#pragma unroll
  for (int i = 0; i < 4; ++i)
#pragma unroll
    for (int j = 0; j < 4; ++j) acc[i][j] = (f32x4){0.f, 0.f, 0.f, 0.f};
  for (int k0 = 0; k0 < 512; k0 += 64) {
    __syncthreads();
#pragma unroll
    for (int j = 0; j < 4; ++j) {
      gl_lds16(srcA[j] + k0, As + (wave * 64 + j * 256) * 8);
      gl_lds16(srcB[j] + k0, Bs + (wave * 64 + j * 256) * 8);
    }
    __builtin_amdgcn_s_waitcnt(0);
    __syncthreads();
#pragma unroll
    for (int ks = 0; ks < 2; ++ks) {
      bf16x8 af[4], bq[4];
#pragma unroll
      for (int mi = 0; mi < 4; ++mi) af[mi] = *(const bf16x8*)(As + offA[mi][ks]);
#pragma unroll
      for (int nj = 0; nj < 4; ++nj) bq[nj] = *(const bf16x8*)(Bs + offB[nj][ks]);
#pragma unroll
      for (int mi = 0; mi < 4; ++mi)
#pragma unroll
        for (int nj = 0; nj < 4; ++nj)
          acc[mi][nj] = __builtin_amdgcn_mfma_f32_16x16x32_bf16(af[mi], bq[nj], acc[mi][nj], 0, 0, 0);
    }
  }
#pragma unroll
  for (int mi = 0; mi < 4; ++mi) {
    const int row0 = bm + wm + mi * 16 + (lane >> 4) * 4;
#pragma unroll
    for (int nj = 0; nj < 4; ++nj) {
      const int col = bn + wn + nj * 16 + fr;   // g = b*1024 + t
      const int b = col >> 10, t = col & 1023;
#pragma unroll
      for (int rr = 0; rr < 4; ++rr)
        out[(size_t)b * 524288 + (size_t)(row0 + rr) * 1024 + t] = acc[mi][nj][rr] + bias[row0 + rr];
    }
  }
}

// ---------------- fused stats: blocks [0,1024) = S+BN partials; [1024,2048) = k logsumexp ----
__global__ __launch_bounds__(256) void stats(const unsigned short* __restrict__ qkv,
                                             const float* __restrict__ PsumT,
                                             float* __restrict__ S,
                                             float* __restrict__ part1,
                                             float* __restrict__ part2,
                                             float* __restrict__ lse) {
  const int bx = blockIdx.x;
  const int tid = threadIdx.x, wave = tid >> 6, lane = tid & 63;
  __shared__ float swave[4][64];
  __shared__ float s_lds[64];
  if (bx < 1024) {
    const int tc = bx & 15, n = bx >> 4;
    const int b = n >> 3, h = n & 7;
    const int t0 = tc * 64;
    const int tg = lane & 7, rg = lane >> 3;
    const unsigned short* qbase = qkv + (size_t)(h * 64) * 8192 + b * 1024 + t0 + tg * 8;
    const float* pbase = PsumT + t0 + tg * 8;
    float acc[8] = {0.f};
#pragma unroll
    for (int i = 0; i < 2; ++i) {
      const int d = wave * 16 + i * 8 + rg;
      bf16x8 qv = *(const bf16x8*)(qbase + (size_t)d * 8192);
      float4 p0 = *(const float4*)(pbase + d * 1024);
      float4 p1 = *(const float4*)(pbase + d * 1024 + 4);
      float p[8] = {p0.x, p0.y, p0.z, p0.w, p1.x, p1.y, p1.z, p1.w};
#pragma unroll
      for (int j = 0; j < 8; ++j) acc[j] = fmaf(bf2f((unsigned short)qv[j]), p[j], acc[j]);
    }
#pragma unroll
    for (int off = 8; off < 64; off <<= 1)
#pragma unroll
      for (int j = 0; j < 8; ++j) acc[j] += __shfl_xor(acc[j], off);
    if (rg == 0) {
#pragma unroll
      for (int j = 0; j < 8; ++j) swave[wave][tg * 8 + j] = acc[j];
    }
    __syncthreads();
    if (tid < 64) {
      float s = swave[0][tid] + swave[1][tid] + swave[2][tid] + swave[3][tid];
      s_lds[tid] = s;
      S[(size_t)n * 1024 + t0 + tid] = s;
    }
    __syncthreads();
    const unsigned short* vbase = qkv + (size_t)(1024 + h * 64) * 8192 + b * 1024 + t0 + tg * 8;
    const int blk = n * 16 + tc;
    float sv[8];
#pragma unroll
    for (int j = 0; j < 8; ++j) sv[j] = s_lds[tg * 8 + j];
#pragma unroll
    for (int i = 0; i < 2; ++i) {
      const int e = wave * 16 + i * 8 + rg;
      bf16x8 vv = *(const bf16x8*)(vbase + (size_t)e * 8192);
      float a1 = 0.f, a2 = 0.f;
#pragma unroll
      for (int j = 0; j < 8; ++j) {
        float val = bf2f((unsigned short)vv[j]) * sv[j];
        a1 += val;
        a2 = fmaf(val, val, a2);
      }
#pragma unroll
      for (int off = 1; off < 8; off <<= 1) {
        a1 += __shfl_xor(a1, off);
        a2 += __shfl_xor(a2, off);
      }
      if (tg == 0) {
        part1[e * 1024 + blk] = a1;
        part2[e * 1024 + blk] = a2;
      }
    }
  } else {
    const int r = (bx - 1024) * 4 + wave;     // 0..4095 = hd*8 + b
    const int hd = r >> 3, b = r & 7;
    const unsigned short* row = qkv + (size_t)(512 + hd) * 8192 + b * 1024 + lane * 16;
    uint4 u0 = *(const uint4*)row;
    uint4 u1 = *(const uint4*)(row + 8);
    const unsigned short* us0 = (const unsigned short*)&u0;
    const unsigned short* us1 = (const unsigned short*)&u1;
    float f[16];
#pragma unroll
    for (int i = 0; i < 8; ++i) { f[i] = bf2f(us0[i]); f[8 + i] = bf2f(us1[i]); }
    float m = f[0];
#pragma unroll
    for (int i = 1; i < 16; ++i) m = fmaxf(m, f[i]);
#pragma unroll
    for (int off = 32; off; off >>= 1) m = fmaxf(m, __shfl_xor(m, off));
    float s = 0.f;
#pragma unroll
    for (int i = 0; i < 16; ++i) s += __expf(f[i] - m);
#pragma unroll
    for (int off = 32; off; off >>= 1) s += __shfl_xor(s, off);
    if (lane == 0) lse[r] = m + __logf(s);
  }
}

// ---------------- context via MFMA with fused softmax-apply ----------------
__global__ __launch_bounds__(256) void context_mfma(const unsigned short* __restrict__ qkv,
                                                    const float* __restrict__ lse,
                                                    float* __restrict__ ctx_part) {
  const int tc = blockIdx.x, n = blockIdx.y;
  const int b = n >> 3, h = n & 7;
  const int tid = threadIdx.x;
  const int wave = tid >> 6, lane = tid & 63;
  __shared__ float ls[64];
  __shared__ float ctx_l[64][68];
  if (tid < 64) ls[tid] = lse[(h * 64 + tid) * 8 + b];
  __syncthreads();
  const int fr = lane & 15, fk = (lane >> 4) * 8;
  const size_t colbase = (size_t)b * 1024 + tc * 256 + wave * 64;
  const unsigned short* kbase = qkv + (size_t)(512 + h * 64) * 8192 + colbase;
  const unsigned short* vbase = qkv + (size_t)(1024 + h * 64) * 8192 + colbase;
  f32x4 acc[4][4];
#pragma unroll
  for (int i = 0; i < 4; ++i)
#pragma unroll
    for (int j = 0; j < 4; ++j) acc[i][j] = (f32x4){0.f, 0.f, 0.f, 0.f};
#pragma unroll
  for (int ks = 0; ks < 2; ++ks) {
    const int tb = ks * 32 + fk;
    bf16x8 aF[4], bF[4];
#pragma unroll
    for (int dt = 0; dt < 4; ++dt) {
      const int row = dt * 16 + fr;
      bf16x8 kv = *(const bf16x8*)(kbase + (size_t)row * 8192 + tb);
      const float lv = ls[row];
      bf16x8 pv;
#pragma unroll
      for (int j = 0; j < 8; ++j)
        pv[j] = (short)f2bf(__expf(bf2f((unsigned short)kv[j]) - lv));
      aF[dt] = pv;
    }
#pragma unroll
    for (int et = 0; et < 4; ++et)
      bF[et] = *(const bf16x8*)(vbase + (size_t)(et * 16 + fr) * 8192 + tb);
#pragma unroll
    for (int dt = 0; dt < 4; ++dt)
#pragma unroll
      for (int et = 0; et < 4; ++et)
        acc[dt][et] = __builtin_amdgcn_mfma_f32_16x16x32_bf16(aF[dt], bF[et], acc[dt][et], 0, 0, 0);
  }
#pragma unroll
  for (int w = 0; w < 4; ++w) {
    if (wave == w) {
#pragma unroll
      for (int dt = 0; dt < 4; ++dt)
#pragma unroll
        for (int et = 0; et < 4; ++et) {
          const int col = et * 16 + fr;
#pragma unroll
          for (int rr = 0; rr < 4; ++rr) {
            const int rw = dt * 16 + (lane >> 4) * 4 + rr;
            if (w == 0) ctx_l[rw][col] = acc[dt][et][rr];
            else ctx_l[rw][col] += acc[dt][et][rr];
          }
        }
    }
    __syncthreads();
  }
  float* outp = ctx_part + ((size_t)tc * 64 + n) * 4096;
  for (int i = tid * 4; i < 4096; i += 1024) {
    const int rw = i >> 6, cc = i & 63;
    *(float4*)(outp + i) = *(const float4*)&ctx_l[rw][cc];
  }
}

// ---------------- fused reduce: blocks [0,256) ctx partials; [256,320) BN final ----------------
__global__ __launch_bounds__(256) void reduce2(const float* __restrict__ part,
                                               float* __restrict__ ctx,
                                               const float* __restrict__ part1,
                                               const float* __restrict__ part2,
                                               const float* __restrict__ gamma,
                                               const float* __restrict__ beta,
                                               float* __restrict__ scale,
                                               float* __restrict__ shift) {
  const int bx = blockIdx.x;
  const int tid = threadIdx.x;
  if (bx < 256) {
    const int i4 = bx * 256 + tid;
    const float4* p = (const float4*)part;
    float4 a = p[i4], b = p[65536 + i4], c = p[131072 + i4], d = p[196608 + i4];
    float4 s = {a.x + b.x + c.x + d.x, a.y + b.y + c.y + d.y,
                a.z + b.z + c.z + d.z, a.w + b.w + c.w + d.w};
    ((float4*)ctx)[i4] = s;
  } else {
    const int e = bx - 256;
    float a1 = 0.f, a2 = 0.f;
#pragma unroll
    for (int i = 0; i < 4; ++i) {
      a1 += part1[e * 1024 + i * 256 + tid];
      a2 += part2[e * 1024 + i * 256 + tid];
    }
#pragma unroll
    for (int off = 32; off; off >>= 1) {
      a1 += __shfl_down(a1, off);
      a2 += __shfl_down(a2, off);
    }
    __shared__ float r1[4], r2[4];
    const int w = tid >> 6, lane = tid & 63;
    if (lane == 0) { r1[w] = a1; r2[w] = a2; }
    __syncthreads();
    if (tid == 0) {
      float s1 = r1[0] + r1[1] + r1[2] + r1[3];
      float s2 = r2[0] + r2[1] + r2[2] + r2[3];
      const float cnt = 65536.0f;
      float mu = s1 / cnt;
      float var = s2 / cnt - mu * mu;
      float sc = gamma[e] * rsqrtf(var + 1e-5f);
      scale[e] = sc;
      shift[e] = beta[e] - mu * sc;
    }
  }
}

// ---------------- fused content + BN-combine + transpose -> outT bf16 ----------------
__global__ __launch_bounds__(256) void content_out_t(const unsigned short* __restrict__ qkv,
                                                     const float* __restrict__ ctx,
                                                     const float* __restrict__ S,
                                                     const float* __restrict__ scale,
                                                     const float* __restrict__ shift,
                                                     unsigned short* __restrict__ outT) {
  const int chunk = blockIdx.x, n = blockIdx.y;   // grid (16, 64)
  const int b = n >> 3, h = n & 7;
  const int t0 = chunk * 64;
  __shared__ float cs[4096];
  __shared__ alignas(16) unsigned short T[64][72];
  const float* cp = ctx + (size_t)n * 4096;
  for (int i = threadIdx.x * 4; i < 4096; i += 1024)
    *(float4*)&cs[i] = *(const float4*)&cp[i];
  __syncthreads();
  const int tid = threadIdx.x;
  const int e0 = (tid & 15) * 4;
  const int tq = (tid >> 4) * 4;
  const unsigned short* qbase = qkv + (size_t)(h * 64) * 8192 + b * 1024 + t0 + tq;
  float acc[4][4] = {{0.f}};
  for (int d = 0; d < 64; ++d) {
    float4 cv = *(const float4*)&cs[d * 64 + e0];
    ushort4 qu = *(const ushort4*)(qbase + (size_t)d * 8192);
    float qa[4] = {bf2f(qu.x), bf2f(qu.y), bf2f(qu.z), bf2f(qu.w)};
    float ca[4] = {cv.x, cv.y, cv.z, cv.w};
#pragma unroll
    for (int a = 0; a < 4; ++a)
#pragma unroll
      for (int c = 0; c < 4; ++c)
        acc[a][c] = fmaf(ca[a], qa[c], acc[a][c]);
  }
  float4 svv = *(const float4*)(S + (size_t)n * 1024 + t0 + tq);
  float sa[4] = {svv.x, svv.y, svv.z, svv.w};
  float4 scv = *(const float4*)(scale + e0);
  float4 shv = *(const float4*)(shift + e0);
  float sc[4] = {scv.x, scv.y, scv.z, scv.w};
  float sh[4] = {shv.x, shv.y, shv.z, shv.w};
#pragma unroll
  for (int a = 0; a < 4; ++a) {
    ushort4 vu = *(const ushort4*)(qkv + (size_t)(1024 + h * 64 + e0 + a) * 8192 + b * 1024 + t0 + tq);
    float va[4] = {bf2f(vu.x), bf2f(vu.y), bf2f(vu.z), bf2f(vu.w)};
#pragma unroll
    for (int c = 0; c < 4; ++c)
      T[tq + c][e0 + a] = f2bf(fmaf(va[c] * sa[c], sc[a], acc[a][c] + sh[a]));
  }
  __syncthreads();
  const int tl = tid >> 2, dq = (tid & 3) * 16;
  uint4 r0 = *(uint4*)&T[tl][dq];
  uint4 r1 = *(uint4*)&T[tl][dq + 8];
  unsigned short* op = outT + ((size_t)(b * 1024 + t0 + tl)) * 512 + h * 64 + dq;
  *(uint4*)op = r0;
  *(uint4*)(op + 8) = r1;
}

extern "C" void kernel_launch(void* const* d_in, const int* in_sizes, int n_in,
                              void* d_out, int out_size, void* d_ws, size_t ws_size,
                              hipStream_t stream) {
  const float* x       = (const float*)d_in[0];
  const float* Wqkv    = (const float*)d_in[1];
  const float* Wout    = (const float*)d_in[2];
  const float* bout    = (const float*)d_in[3];
  const float* relpos  = (const float*)d_in[4];
  const float* gamma   = (const float*)d_in[5];
  const float* beta    = (const float*)d_in[6];
  float* out = (float*)d_out;

  float* ws = (float*)d_ws;
  unsigned short* qkvb  = (unsigned short*)ws;             // 1536*8192 bf16
  float* p = ws + 6291456;
  unsigned short* xb    = (unsigned short*)p;  p += 2097152;   // 8192x512 bf16
  unsigned short* wqkvb = (unsigned short*)p;  p += 393216;    // 1536x512 bf16
  unsigned short* woutb = (unsigned short*)p;  p += 131072;    // 512x512 bf16
  float* ctx_part = p;  p += 1048576;                          // 4*64*4096
  float* ctx      = p;  p += 262144;
  float* PsumT    = p;  p += 65536;
  float* S        = p;  p += 65536;
  float* lse      = p;  p += 4096;
  float* part1    = p;  p += 65536;
  float* part2    = p;  p += 65536;
  float* scale    = p;  p += 64;
  float* shift    = p;  p += 64;
  unsigned short* outT = (unsigned short*)p;                   // 8192x512 bf16

  // 0. prep: cast inputs + PsumT
  prep<<<5376, 256, 0, stream>>>(x, Wqkv, Wout, relpos, xb, wqkvb, woutb, PsumT);
  // 1. qkv (bf16) = Wqkv @ x^T, BK=64 global_load_lds GEMM
  gemm_qkv<<<dim3(64, 12), 256, 0, stream>>>(wqkvb, xb, qkvb);
  // 2. fused stats: S + BN partials, k-row logsumexp
  stats<<<2048, 256, 0, stream>>>(qkvb, PsumT, S, part1, part2, lse);
  // 3. context via MFMA with fused softmax-apply
  context_mfma<<<dim3(4, 64), 256, 0, stream>>>(qkvb, lse, ctx_part);
  // 4. fused reduce: ctx partials + BN final
  reduce2<<<320, 256, 0, stream>>>(ctx_part, ctx, part1, part2, gamma, beta, scale, shift);
  // 5. fused content + BN-combine + transpose
  content_out_t<<<dim3(16, 64), 256, 0, stream>>>(qkvb, ctx, S, scale, shift, outT);
  // 6. final GEMM: out = Wout @ comb + bout
  gemm_out<<<dim3(64, 4), 256, 0, stream>>>(woutb, outT, bout, out);
}